// Round 5
// baseline (169.985 us; speedup 1.0000x reference)
//
#include <hip/hip_runtime.h>
#include <cstdint>
#include <cstddef>

#define LNUM 8
#define NTOK 8192
#define HDIM 768
#define IDIM 1536

typedef __bf16 bf16x8 __attribute__((ext_vector_type(8)));
typedef float f32x4 __attribute__((ext_vector_type(4)));

__device__ __forceinline__ void gload16(void* lds, const void* gsrc) {
  __builtin_amdgcn_global_load_lds(
      (const __attribute__((address_space(1))) void*)gsrc,
      (__attribute__((address_space(3))) void*)lds, 16, 0, 0);
}

// fast GELU: x * sigmoid(2u), u = 0.79788456*(x + 0.044715 x^3)
__device__ __forceinline__ float gelu_f(float x) {
  float xx = x * x;
  float u = x * __builtin_fmaf(0.0356774081f, xx, 0.7978845608f);
  float t = __builtin_exp2f(-2.8853900817779268f * u);  // e^{-2u}
  return x * __builtin_amdgcn_rcpf(1.0f + t);
}

// ---------------- grouping kernels ----------------
// meta ints: [0..7]=counts, [8..15]=cursor, [16..24]=offs, [25..33]=tileOffs128
__global__ void hist_kernel(const int* __restrict__ lid, int* __restrict__ meta) {
  __shared__ int c[LNUM];
  if (threadIdx.x < LNUM) c[threadIdx.x] = 0;
  __syncthreads();
  int i = blockIdx.x * blockDim.x + threadIdx.x;
  atomicAdd(&c[lid[i]], 1);
  __syncthreads();
  if (threadIdx.x < LNUM) atomicAdd(&meta[threadIdx.x], c[threadIdx.x]);
}

__global__ void scan_kernel(int* __restrict__ meta) {
  if (threadIdx.x == 0) {
    int o = 0, t = 0;
    for (int e = 0; e < LNUM; ++e) {
      meta[16 + e] = o;
      meta[25 + e] = t;
      o += meta[e];
      t += (meta[e] + 127) >> 7;
    }
    meta[16 + LNUM] = o;
    meta[25 + LNUM] = t;
  }
}

__global__ void scatter_kernel(const int* __restrict__ lid, int* __restrict__ meta,
                               int* __restrict__ perm) {
  int i = blockIdx.x * blockDim.x + threadIdx.x;
  int e = lid[i];
  int pos = atomicAdd(&meta[8 + e], 1);
  perm[meta[16 + e] + pos] = i;
}

// ---------------- conversion kernels ----------------
__global__ void conv_z_kernel(const float4* __restrict__ z, bf16x8* __restrict__ zb) {
  int i = blockIdx.x * 256 + threadIdx.x;
  float4 a = z[i * 2], b = z[i * 2 + 1];
  bf16x8 o;
  o[0] = (__bf16)a.x; o[1] = (__bf16)a.y; o[2] = (__bf16)a.z; o[3] = (__bf16)a.w;
  o[4] = (__bf16)b.x; o[5] = (__bf16)b.y; o[6] = (__bf16)b.z; o[7] = (__bf16)b.w;
  zb[i] = o;
}

// in: [L][R][C] f32 -> out: [L][C][R] bf16 (transpose + convert), 64x64 tiles
__global__ __launch_bounds__(256) void transpose_cvt_kernel(
    const float* __restrict__ in, __bf16* __restrict__ out, int R, int C) {
  __shared__ float tile[64][65];
  int e = blockIdx.z;
  int c0 = blockIdx.x * 64, r0 = blockIdx.y * 64;
  const float* src = in + (size_t)e * R * C;
  __bf16* dst = out + (size_t)e * R * C;
  int t = threadIdx.x;
  int rr = t >> 4, cc = (t & 15) << 2;
  #pragma unroll
  for (int it = 0; it < 4; ++it) {
    float4 v = *(const float4*)&src[(size_t)(r0 + rr + it * 16) * C + c0 + cc];
    tile[rr + it * 16][cc] = v.x;
    tile[rr + it * 16][cc + 1] = v.y;
    tile[rr + it * 16][cc + 2] = v.z;
    tile[rr + it * 16][cc + 3] = v.w;
  }
  __syncthreads();
  int c = t >> 2, rcb = (t & 3) << 3;
  #pragma unroll
  for (int it = 0; it < 2; ++it) {
    int r = rcb + it * 32;
    bf16x8 o;
    #pragma unroll
    for (int j = 0; j < 8; ++j) o[j] = (__bf16)tile[r + j][c];
    *(bf16x8*)&dst[(size_t)(c0 + c) * R + r0 + r] = o;
  }
}

// ---------------- grouped GEMM 1: act = gelu(zb[perm] @ w1t^T + b1) ----------------
// BK=32, 5-slot LDS ring, prefetch depth 3, counted vmcnt(12), raw s_barrier.
// LDS rows 32 elems (64B); swizzle: Ls[r][g*8+j] = G[r][(g^((r>>1)&3))*8+j]
__global__ __launch_bounds__(256) void gemm1_kernel(
    const __bf16* __restrict__ zb, const __bf16* __restrict__ w1t,
    const float* __restrict__ b1, const int* __restrict__ meta,
    const int* __restrict__ perm, __bf16* __restrict__ act) {
  __shared__ __bf16 As[5][128 * 32];
  __shared__ __bf16 Bs[5][128 * 32];
  const int* offs = meta + 16;
  const int* tiles = meta + 25;
  int nwg = gridDim.x;
  int bid = blockIdx.x;
  int tileid = (bid & 7) * (nwg >> 3) + (bid >> 3);  // XCD chunking (nwg%8==0)
  int bx = tileid % (IDIM / 128);
  int t = tileid / (IDIM / 128);
  if (t >= tiles[LNUM]) return;
  int e = 0;
  #pragma unroll
  for (int q = 0; q < LNUM - 1; ++q)
    if (t >= tiles[e + 1]) ++e;
  int mtile = t - tiles[e];
  int row0 = offs[e] + (mtile << 7);
  int cntRem = offs[e + 1] - row0;
  if (cntRem > 128) cntRem = 128;
  int n0 = bx << 7;
  int tid = threadIdx.x, lane = tid & 63, wv = tid >> 6;
  int wr = wv >> 1, wc = wv & 1;

  // stage-side pre-swizzled global elem offset (within 32-elem K-window)
  int srcElem = (((lane & 3) ^ ((lane >> 3) & 3)) << 3);

  const __bf16* srcA[2];
  const __bf16* srcB[2];
  #pragma unroll
  for (int i = 0; i < 2; ++i) {
    int row = ((wv * 2 + i) << 4) + (lane >> 2);
    int rA = row < cntRem ? row : cntRem - 1;
    int tok = perm[row0 + rA];
    srcA[i] = zb + (size_t)tok * HDIM + srcElem;
    srcB[i] = w1t + ((size_t)e * IDIM + n0 + row) * HDIM + srcElem;
  }

  // read-side swizzled elem offset within a 32-elem LDS row
  int rdElem = (((lane >> 4) ^ ((lane >> 1) & 3)) << 3);
  f32x4 acc[4][4] = {};

#define STAGE1(slotv, ksv)                                                    \
  do {                                                                        \
    int _o = (ksv) * 32;                                                      \
    _Pragma("unroll") for (int i = 0; i < 2; ++i) {                           \
      gload16((char*)As[slotv] + (((wv << 1) + i) << 10), srcA[i] + _o);      \
      gload16((char*)Bs[slotv] + (((wv << 1) + i) << 10), srcB[i] + _o);      \
    }                                                                         \
  } while (0)

  const int NSTEP = HDIM / 32;  // 24
  STAGE1(0, 0);
  STAGE1(1, 1);
  STAGE1(2, 2);
  int slot = 0, pslot = 3;
  for (int kk = 0; kk < NSTEP; ++kk) {
    int ks = (kk + 3 < NSTEP) ? kk + 3 : NSTEP - 1;  // clamp: keep 4 loads/iter
    STAGE1(pslot, ks);
    __builtin_amdgcn_sched_barrier(0);
    asm volatile("s_waitcnt vmcnt(12)\n\ts_barrier" ::: "memory");
    __builtin_amdgcn_sched_barrier(0);
    bf16x8 a[4], b[4];
    #pragma unroll
    for (int mi = 0; mi < 4; ++mi)
      a[mi] = *(const bf16x8*)&As[slot][((wr * 64 + mi * 16 + (lane & 15)) << 5) + rdElem];
    #pragma unroll
    for (int ni = 0; ni < 4; ++ni)
      b[ni] = *(const bf16x8*)&Bs[slot][((wc * 64 + ni * 16 + (lane & 15)) << 5) + rdElem];
    __builtin_amdgcn_s_setprio(1);
    #pragma unroll
    for (int mi = 0; mi < 4; ++mi)
      #pragma unroll
      for (int ni = 0; ni < 4; ++ni)
        acc[mi][ni] = __builtin_amdgcn_mfma_f32_16x16x32_bf16(a[mi], b[ni], acc[mi][ni], 0, 0, 0);
    __builtin_amdgcn_s_setprio(0);
    slot = (slot == 4) ? 0 : slot + 1;
    pslot = (pslot == 4) ? 0 : pslot + 1;
  }
  asm volatile("s_waitcnt vmcnt(0)" ::: "memory");
  __syncthreads();

  float bb[4];
  #pragma unroll
  for (int ni = 0; ni < 4; ++ni)
    bb[ni] = b1[e * IDIM + n0 + wc * 64 + ni * 16 + (lane & 15)];

  #pragma unroll
  for (int mi = 0; mi < 4; ++mi) {
    int gr0 = wr * 64 + mi * 16 + ((lane >> 4) << 2);
    #pragma unroll
    for (int r = 0; r < 4; ++r) {
      int g = gr0 + r;
      if (g < cntRem) {
        size_t p = (size_t)(row0 + g);
        #pragma unroll
        for (int ni = 0; ni < 4; ++ni) {
          int col = n0 + wc * 64 + ni * 16 + (lane & 15);
          act[p * IDIM + col] = (__bf16)gelu_f(acc[mi][ni][r] + bb[ni]);
        }
      }
    }
  }
#undef STAGE1
}

// ---------------- grouped GEMM 2: out[tok] = z[tok] + act @ w2t^T + b2 ----------------
__global__ __launch_bounds__(256) void gemm2_kernel(
    const __bf16* __restrict__ act, const __bf16* __restrict__ w2t,
    const float* __restrict__ b2, const float* __restrict__ z,
    const int* __restrict__ meta, const int* __restrict__ perm,
    float* __restrict__ out) {
  __shared__ __bf16 As[5][128 * 32];
  __shared__ __bf16 Bs[5][128 * 32];
  const int* offs = meta + 16;
  const int* tiles = meta + 25;
  int nwg = gridDim.x;
  int bid = blockIdx.x;
  int tileid = (bid & 7) * (nwg >> 3) + (bid >> 3);
  int bx = tileid % (HDIM / 128);
  int t = tileid / (HDIM / 128);
  if (t >= tiles[LNUM]) return;
  int e = 0;
  #pragma unroll
  for (int q = 0; q < LNUM - 1; ++q)
    if (t >= tiles[e + 1]) ++e;
  int mtile = t - tiles[e];
  int row0 = offs[e] + (mtile << 7);
  int cntRem = offs[e + 1] - row0;
  if (cntRem > 128) cntRem = 128;
  int n0 = bx << 7;
  int tid = threadIdx.x, lane = tid & 63, wv = tid >> 6;
  int wr = wv >> 1, wc = wv & 1;

  int srcElem = (((lane & 3) ^ ((lane >> 3) & 3)) << 3);

  const __bf16* srcA[2];
  const __bf16* srcB[2];
  #pragma unroll
  for (int i = 0; i < 2; ++i) {
    int row = ((wv * 2 + i) << 4) + (lane >> 2);
    int rA = row < cntRem ? row : cntRem - 1;
    srcA[i] = act + (size_t)(row0 + rA) * IDIM + srcElem;
    srcB[i] = w2t + ((size_t)e * HDIM + n0 + row) * IDIM + srcElem;
  }

  int rdElem = (((lane >> 4) ^ ((lane >> 1) & 3)) << 3);
  f32x4 acc[4][4] = {};

#define STAGE2(slotv, ksv)                                                    \
  do {                                                                        \
    int _o = (ksv) * 32;                                                      \
    _Pragma("unroll") for (int i = 0; i < 2; ++i) {                           \
      gload16((char*)As[slotv] + (((wv << 1) + i) << 10), srcA[i] + _o);      \
      gload16((char*)Bs[slotv] + (((wv << 1) + i) << 10), srcB[i] + _o);      \
    }                                                                         \
  } while (0)

  const int NSTEP = IDIM / 32;  // 48
  STAGE2(0, 0);
  STAGE2(1, 1);
  STAGE2(2, 2);
  int slot = 0, pslot = 3;
  for (int kk = 0; kk < NSTEP; ++kk) {
    int ks = (kk + 3 < NSTEP) ? kk + 3 : NSTEP - 1;
    STAGE2(pslot, ks);
    __builtin_amdgcn_sched_barrier(0);
    asm volatile("s_waitcnt vmcnt(12)\n\ts_barrier" ::: "memory");
    __builtin_amdgcn_sched_barrier(0);
    bf16x8 a[4], b[4];
    #pragma unroll
    for (int mi = 0; mi < 4; ++mi)
      a[mi] = *(const bf16x8*)&As[slot][((wr * 64 + mi * 16 + (lane & 15)) << 5) + rdElem];
    #pragma unroll
    for (int ni = 0; ni < 4; ++ni)
      b[ni] = *(const bf16x8*)&Bs[slot][((wc * 64 + ni * 16 + (lane & 15)) << 5) + rdElem];
    __builtin_amdgcn_s_setprio(1);
    #pragma unroll
    for (int mi = 0; mi < 4; ++mi)
      #pragma unroll
      for (int ni = 0; ni < 4; ++ni)
        acc[mi][ni] = __builtin_amdgcn_mfma_f32_16x16x32_bf16(a[mi], b[ni], acc[mi][ni], 0, 0, 0);
    __builtin_amdgcn_s_setprio(0);
    slot = (slot == 4) ? 0 : slot + 1;
    pslot = (pslot == 4) ? 0 : pslot + 1;
  }
  asm volatile("s_waitcnt vmcnt(0)" ::: "memory");
  __syncthreads();

  float bb[4];
  #pragma unroll
  for (int ni = 0; ni < 4; ++ni)
    bb[ni] = b2[e * HDIM + n0 + wc * 64 + ni * 16 + (lane & 15)];

  #pragma unroll
  for (int mi = 0; mi < 4; ++mi) {
    int gr0 = wr * 64 + mi * 16 + ((lane >> 4) << 2);
    #pragma unroll
    for (int r = 0; r < 4; ++r) {
      int g = gr0 + r;
      if (g < cntRem) {
        int p = row0 + g;
        int tok = perm[p];
        #pragma unroll
        for (int ni = 0; ni < 4; ++ni) {
          int col = n0 + wc * 64 + ni * 16 + (lane & 15);
          out[(size_t)tok * HDIM + col] =
              z[(size_t)tok * HDIM + col] + acc[mi][ni][r] + bb[ni];
        }
      }
    }
  }
#undef STAGE2
}

extern "C" void kernel_launch(void* const* d_in, const int* in_sizes, int n_in,
                              void* d_out, int out_size, void* d_ws, size_t ws_size,
                              hipStream_t stream) {
  const float* z  = (const float*)d_in[0];
  const int*   lid = (const int*)d_in[1];
  const float* w1 = (const float*)d_in[2];
  const float* b1 = (const float*)d_in[3];
  const float* w2 = (const float*)d_in[4];
  const float* b2 = (const float*)d_in[5];
  float* out = (float*)d_out;
  char* ws = (char*)d_ws;

  int* meta = (int*)ws;             // 34 ints
  int* perm = (int*)(ws + 256);     // NTOK ints
  __bf16* zb  = (__bf16*)(ws + 33280);
  __bf16* w1t = zb + (size_t)NTOK * HDIM;
  __bf16* w2t = w1t + (size_t)LNUM * HDIM * IDIM;
  __bf16* act = w2t + (size_t)LNUM * HDIM * IDIM;

  hipMemsetAsync(meta, 0, 64, stream);
  hist_kernel<<<NTOK / 256, 256, 0, stream>>>(lid, meta);
  scan_kernel<<<1, 64, 0, stream>>>(meta);
  scatter_kernel<<<NTOK / 256, 256, 0, stream>>>(lid, meta, perm);
  conv_z_kernel<<<(NTOK * HDIM / 8) / 256, 256, 0, stream>>>((const float4*)z, (bf16x8*)zb);
  transpose_cvt_kernel<<<dim3(IDIM / 64, HDIM / 64, LNUM), 256, 0, stream>>>(w1, w1t, HDIM, IDIM);
  transpose_cvt_kernel<<<dim3(HDIM / 64, IDIM / 64, LNUM), 256, 0, stream>>>(w2, w2t, IDIM, HDIM);
  gemm1_kernel<<<(IDIM / 128) * 72, 256, 0, stream>>>(zb, w1t, b1, meta, perm, act);
  gemm2_kernel<<<(HDIM / 128) * 72, 256, 0, stream>>>(act, w2t, b2, z, meta, perm, out);
}

// Round 6
// 117.463 us; speedup vs baseline: 1.4471x; 1.4471x over previous
//
#include <hip/hip_runtime.h>
#include <cstdint>
#include <cstddef>

#define LNUM 8
#define NTOK 8192
#define HDIM 768
#define IDIM 1536

typedef __bf16 bf16x8 __attribute__((ext_vector_type(8)));
typedef float f32x4 __attribute__((ext_vector_type(4)));

__device__ __forceinline__ void gload16(void* lds, const void* gsrc) {
  __builtin_amdgcn_global_load_lds(
      (const __attribute__((address_space(1))) void*)gsrc,
      (__attribute__((address_space(3))) void*)lds, 16, 0, 0);
}

// fast GELU: x * sigmoid(2u), u = 0.79788456*(x + 0.044715 x^3)
__device__ __forceinline__ float gelu_f(float x) {
  float xx = x * x;
  float u = x * __builtin_fmaf(0.0356774081f, xx, 0.7978845608f);
  float t = __builtin_exp2f(-2.8853900817779268f * u);  // e^{-2u}
  return x * __builtin_amdgcn_rcpf(1.0f + t);
}

// meta layout (ints): [0..255] per-block hist (32 blocks x 8 experts)
//                     [256..264] offs, [265..273] tileOffs128
// K1: per-block histogram, plain stores (no global zero-init needed)
__global__ void hist_kernel(const int* __restrict__ lid, int* __restrict__ meta) {
  __shared__ int c[LNUM];
  if (threadIdx.x < LNUM) c[threadIdx.x] = 0;
  __syncthreads();
  int i = blockIdx.x * 256 + threadIdx.x;
  atomicAdd(&c[lid[i]], 1);
  __syncthreads();
  if (threadIdx.x < LNUM) meta[blockIdx.x * LNUM + threadIdx.x] = c[threadIdx.x];
}

// transpose+convert one 64x64 tile: dst[C][R] (bf16) <- src[R][C] (f32)
__device__ __forceinline__ void tr_cvt_tile(float (*tile)[65], const float* src,
                                            __bf16* dst, int R, int C, int r0,
                                            int c0, int t) {
  int rr = t >> 4, cc = (t & 15) << 2;
  #pragma unroll
  for (int it = 0; it < 4; ++it) {
    float4 v = *(const float4*)&src[(size_t)(r0 + rr + it * 16) * C + c0 + cc];
    tile[rr + it * 16][cc] = v.x;
    tile[rr + it * 16][cc + 1] = v.y;
    tile[rr + it * 16][cc + 2] = v.z;
    tile[rr + it * 16][cc + 3] = v.w;
  }
  __syncthreads();
  int c = t >> 2, rcb = (t & 3) << 3;
  #pragma unroll
  for (int it = 0; it < 2; ++it) {
    int r = rcb + it * 32;
    bf16x8 o;
    #pragma unroll
    for (int j = 0; j < 8; ++j) o[j] = (__bf16)tile[r + j][c];
    *(bf16x8*)&dst[(size_t)(c0 + c) * R + r0 + r] = o;
  }
}

// K2 megaprep: blocks [0,32) scatter (+offs/tiles by block 0),
// [32,3104) conv_z, [3104,5408) w1 transpose, [5408,7712) w2 transpose
#define NB_SC 32
#define NB_CZ 3072
#define NB_W 2304
__global__ __launch_bounds__(256) void megaprep_kernel(
    const int* __restrict__ lid, const float* __restrict__ z,
    const float* __restrict__ w1, const float* __restrict__ w2,
    int* __restrict__ meta, int* __restrict__ perm, bf16x8* __restrict__ zb,
    __bf16* __restrict__ w1t, __bf16* __restrict__ w2t) {
  __shared__ float tile[64][65];
  __shared__ int lcnt[LNUM], lbase[LNUM];
  int bxid = blockIdx.x;
  int tid = threadIdx.x;
  if (bxid < NB_SC) {
    // ---- scatter ----
    int b = bxid;
    if (tid < LNUM) {
      lcnt[tid] = 0;
      int e = tid, base = 0;
      for (int ee = 0; ee < e; ++ee) {
        int s = 0;
        for (int bb = 0; bb < 32; ++bb) s += meta[bb * LNUM + ee];
        base += s;
      }
      for (int bb = 0; bb < b; ++bb) base += meta[bb * LNUM + tid];
      lbase[tid] = base;
    }
    __syncthreads();
    int i = b * 256 + tid;
    int e = lid[i];
    int r = atomicAdd(&lcnt[e], 1);
    perm[lbase[e] + r] = i;
    if (b == 0 && tid == 0) {
      int o = 0, tt = 0;
      for (int e2 = 0; e2 < LNUM; ++e2) {
        int s = 0;
        for (int bb = 0; bb < 32; ++bb) s += meta[bb * LNUM + e2];
        meta[256 + e2] = o;
        meta[265 + e2] = tt;
        o += s;
        tt += (s + 127) >> 7;
      }
      meta[264] = o;
      meta[273] = tt;
    }
  } else if (bxid < NB_SC + NB_CZ) {
    // ---- conv z -> bf16 ----
    int i = (bxid - NB_SC) * 256 + tid;
    const float4* zf = (const float4*)z;
    float4 a = zf[i * 2], b4 = zf[i * 2 + 1];
    bf16x8 o;
    o[0] = (__bf16)a.x; o[1] = (__bf16)a.y; o[2] = (__bf16)a.z; o[3] = (__bf16)a.w;
    o[4] = (__bf16)b4.x; o[5] = (__bf16)b4.y; o[6] = (__bf16)b4.z; o[7] = (__bf16)b4.w;
    zb[i] = o;
  } else if (bxid < NB_SC + NB_CZ + NB_W) {
    // ---- w1 [H][I] -> w1t [I][H] ----
    int idx = bxid - (NB_SC + NB_CZ);
    int e = idx / 288, rem = idx % 288;
    int c0 = (rem % 24) * 64, r0 = (rem / 24) * 64;
    tr_cvt_tile(tile, w1 + (size_t)e * HDIM * IDIM, w1t + (size_t)e * HDIM * IDIM,
                HDIM, IDIM, r0, c0, tid);
  } else {
    // ---- w2 [I][H] -> w2t [H][I] ----
    int idx = bxid - (NB_SC + NB_CZ + NB_W);
    int e = idx / 288, rem = idx % 288;
    int c0 = (rem % 12) * 64, r0 = (rem / 12) * 64;
    tr_cvt_tile(tile, w2 + (size_t)e * HDIM * IDIM, w2t + (size_t)e * HDIM * IDIM,
                IDIM, HDIM, r0, c0, tid);
  }
}

// ---------------- grouped GEMM 1: act = gelu(zb[perm] @ w1t^T + b1) ----------------
// 1-D grid (864), XCD-chunk swizzled; LDS double-buffered 2-phase prefetch.
// LDS rows 64 elems; content swizzled: Ls[r][c] = G[r][c ^ ((r&7)<<3)]
__global__ __launch_bounds__(256) void gemm1_kernel(
    const __bf16* __restrict__ zb, const __bf16* __restrict__ w1t,
    const float* __restrict__ b1, const int* __restrict__ meta,
    const int* __restrict__ perm, __bf16* __restrict__ act) {
  __shared__ __bf16 As[2][128 * 64];
  __shared__ __bf16 Bs[2][128 * 64];
  const int* offs = meta + 256;
  const int* tiles = meta + 265;
  int nwg = gridDim.x;
  int bid = blockIdx.x;
  int tileid = (bid & 7) * (nwg >> 3) + (bid >> 3);  // XCD chunking (nwg%8==0)
  int bx = tileid % (IDIM / 128);
  int t = tileid / (IDIM / 128);
  if (t >= tiles[LNUM]) return;
  int e = 0;
  #pragma unroll
  for (int q = 0; q < LNUM - 1; ++q)
    if (t >= tiles[e + 1]) ++e;
  int mtile = t - tiles[e];
  int row0 = offs[e] + (mtile << 7);
  int cntRem = offs[e + 1] - row0;
  if (cntRem > 128) cntRem = 128;
  int n0 = bx << 7;
  int tid = threadIdx.x, lane = tid & 63, wv = tid >> 6;
  int wr = wv >> 1, wc = wv & 1;
  int swz = ((lane & 7) ^ (lane >> 3)) << 3;  // pre-swizzled global elem offset

  const __bf16* srcA[4];
  const __bf16* srcB[4];
  #pragma unroll
  for (int i = 0; i < 4; ++i) {
    int row = ((wv * 4 + i) << 3) + (lane >> 3);
    int rA = row < cntRem ? row : cntRem - 1;
    int tok = perm[row0 + rA];
    srcA[i] = zb + (size_t)tok * HDIM + swz;
    srcB[i] = w1t + ((size_t)e * IDIM + n0 + row) * HDIM + swz;
  }

  int rswz = (lane & 7) << 3;
  f32x4 acc[4][4] = {};

  #pragma unroll
  for (int i = 0; i < 4; ++i) {
    gload16((char*)As[0] + ((wv * 4 + i) << 10), srcA[i]);
    gload16((char*)Bs[0] + ((wv * 4 + i) << 10), srcB[i]);
  }
  __syncthreads();

  int cur = 0;
  for (int kk = 0; kk < HDIM / 64; ++kk) {
    if (kk + 1 < HDIM / 64) {
      #pragma unroll
      for (int i = 0; i < 4; ++i) {
        gload16((char*)As[cur ^ 1] + ((wv * 4 + i) << 10), srcA[i] + (kk + 1) * 64);
        gload16((char*)Bs[cur ^ 1] + ((wv * 4 + i) << 10), srcB[i] + (kk + 1) * 64);
      }
    }
    #pragma unroll
    for (int k2 = 0; k2 < 2; ++k2) {
      int kb = (k2 * 32 + ((lane >> 4) << 3)) ^ rswz;
      bf16x8 a[4], b[4];
      #pragma unroll
      for (int mi = 0; mi < 4; ++mi)
        a[mi] = *(const bf16x8*)&As[cur][((wr * 64 + mi * 16 + (lane & 15)) << 6) + kb];
      #pragma unroll
      for (int ni = 0; ni < 4; ++ni)
        b[ni] = *(const bf16x8*)&Bs[cur][((wc * 64 + ni * 16 + (lane & 15)) << 6) + kb];
      #pragma unroll
      for (int mi = 0; mi < 4; ++mi)
        #pragma unroll
        for (int ni = 0; ni < 4; ++ni)
          acc[mi][ni] = __builtin_amdgcn_mfma_f32_16x16x32_bf16(a[mi], b[ni], acc[mi][ni], 0, 0, 0);
    }
    __syncthreads();
    cur ^= 1;
  }

  float bb[4];
  #pragma unroll
  for (int ni = 0; ni < 4; ++ni)
    bb[ni] = b1[e * IDIM + n0 + wc * 64 + ni * 16 + (lane & 15)];

  #pragma unroll
  for (int mi = 0; mi < 4; ++mi) {
    int gr0 = wr * 64 + mi * 16 + ((lane >> 4) << 2);
    #pragma unroll
    for (int r = 0; r < 4; ++r) {
      int g = gr0 + r;
      if (g < cntRem) {
        size_t p = (size_t)(row0 + g);
        #pragma unroll
        for (int ni = 0; ni < 4; ++ni) {
          int col = n0 + wc * 64 + ni * 16 + (lane & 15);
          act[p * IDIM + col] = (__bf16)gelu_f(acc[mi][ni][r] + bb[ni]);
        }
      }
    }
  }
}

// ---------------- grouped GEMM 2: out[tok] = z[tok] + act @ w2t^T + b2 ----------------
__global__ __launch_bounds__(256) void gemm2_kernel(
    const __bf16* __restrict__ act, const __bf16* __restrict__ w2t,
    const float* __restrict__ b2, const float* __restrict__ z,
    const int* __restrict__ meta, const int* __restrict__ perm,
    float* __restrict__ out) {
  __shared__ __bf16 As[2][128 * 64];
  __shared__ __bf16 Bs[2][128 * 64];
  const int* offs = meta + 256;
  const int* tiles = meta + 265;
  int nwg = gridDim.x;
  int bid = blockIdx.x;
  int tileid = (bid & 7) * (nwg >> 3) + (bid >> 3);
  int bx = tileid % (HDIM / 128);
  int t = tileid / (HDIM / 128);
  if (t >= tiles[LNUM]) return;
  int e = 0;
  #pragma unroll
  for (int q = 0; q < LNUM - 1; ++q)
    if (t >= tiles[e + 1]) ++e;
  int mtile = t - tiles[e];
  int row0 = offs[e] + (mtile << 7);
  int cntRem = offs[e + 1] - row0;
  if (cntRem > 128) cntRem = 128;
  int n0 = bx << 7;
  int tid = threadIdx.x, lane = tid & 63, wv = tid >> 6;
  int wr = wv >> 1, wc = wv & 1;
  int swz = ((lane & 7) ^ (lane >> 3)) << 3;

  const __bf16* srcA[4];
  const __bf16* srcB[4];
  #pragma unroll
  for (int i = 0; i < 4; ++i) {
    int row = ((wv * 4 + i) << 3) + (lane >> 3);
    int rA = row < cntRem ? row : cntRem - 1;
    srcA[i] = act + (size_t)(row0 + rA) * IDIM + swz;
    srcB[i] = w2t + ((size_t)e * HDIM + n0 + row) * IDIM + swz;
  }

  int rswz = (lane & 7) << 3;
  f32x4 acc[4][4] = {};

  #pragma unroll
  for (int i = 0; i < 4; ++i) {
    gload16((char*)As[0] + ((wv * 4 + i) << 10), srcA[i]);
    gload16((char*)Bs[0] + ((wv * 4 + i) << 10), srcB[i]);
  }
  __syncthreads();

  int cur = 0;
  for (int kk = 0; kk < IDIM / 64; ++kk) {
    if (kk + 1 < IDIM / 64) {
      #pragma unroll
      for (int i = 0; i < 4; ++i) {
        gload16((char*)As[cur ^ 1] + ((wv * 4 + i) << 10), srcA[i] + (kk + 1) * 64);
        gload16((char*)Bs[cur ^ 1] + ((wv * 4 + i) << 10), srcB[i] + (kk + 1) * 64);
      }
    }
    #pragma unroll
    for (int k2 = 0; k2 < 2; ++k2) {
      int kb = (k2 * 32 + ((lane >> 4) << 3)) ^ rswz;
      bf16x8 a[4], b[4];
      #pragma unroll
      for (int mi = 0; mi < 4; ++mi)
        a[mi] = *(const bf16x8*)&As[cur][((wr * 64 + mi * 16 + (lane & 15)) << 6) + kb];
      #pragma unroll
      for (int ni = 0; ni < 4; ++ni)
        b[ni] = *(const bf16x8*)&Bs[cur][((wc * 64 + ni * 16 + (lane & 15)) << 6) + kb];
      #pragma unroll
      for (int mi = 0; mi < 4; ++mi)
        #pragma unroll
        for (int ni = 0; ni < 4; ++ni)
          acc[mi][ni] = __builtin_amdgcn_mfma_f32_16x16x32_bf16(a[mi], b[ni], acc[mi][ni], 0, 0, 0);
    }
    __syncthreads();
    cur ^= 1;
  }

  float bb[4];
  #pragma unroll
  for (int ni = 0; ni < 4; ++ni)
    bb[ni] = b2[e * HDIM + n0 + wc * 64 + ni * 16 + (lane & 15)];

  #pragma unroll
  for (int mi = 0; mi < 4; ++mi) {
    int gr0 = wr * 64 + mi * 16 + ((lane >> 4) << 2);
    #pragma unroll
    for (int r = 0; r < 4; ++r) {
      int g = gr0 + r;
      if (g < cntRem) {
        int p = row0 + g;
        int tok = perm[p];
        #pragma unroll
        for (int ni = 0; ni < 4; ++ni) {
          int col = n0 + wc * 64 + ni * 16 + (lane & 15);
          out[(size_t)tok * HDIM + col] =
              z[(size_t)tok * HDIM + col] + acc[mi][ni][r] + bb[ni];
        }
      }
    }
  }
}

extern "C" void kernel_launch(void* const* d_in, const int* in_sizes, int n_in,
                              void* d_out, int out_size, void* d_ws, size_t ws_size,
                              hipStream_t stream) {
  const float* z  = (const float*)d_in[0];
  const int*   lid = (const int*)d_in[1];
  const float* w1 = (const float*)d_in[2];
  const float* b1 = (const float*)d_in[3];
  const float* w2 = (const float*)d_in[4];
  const float* b2 = (const float*)d_in[5];
  float* out = (float*)d_out;
  char* ws = (char*)d_ws;

  int* meta = (int*)ws;                     // 274 ints (hist 256 + offs 9 + tiles 9)
  int* perm = (int*)(ws + 2048);            // NTOK ints
  __bf16* zb  = (__bf16*)(ws + 2048 + 32768);
  __bf16* w1t = zb + (size_t)NTOK * HDIM;
  __bf16* w2t = w1t + (size_t)LNUM * HDIM * IDIM;
  __bf16* act = w2t + (size_t)LNUM * HDIM * IDIM;

  hist_kernel<<<NTOK / 256, 256, 0, stream>>>(lid, meta);
  megaprep_kernel<<<NB_SC + NB_CZ + 2 * NB_W, 256, 0, stream>>>(
      lid, z, w1, w2, meta, perm, (bf16x8*)zb, w1t, w2t);
  gemm1_kernel<<<(IDIM / 128) * 72, 256, 0, stream>>>(zb, w1t, b1, meta, perm, act);
  gemm2_kernel<<<(HDIM / 128) * 72, 256, 0, stream>>>(act, w2t, b2, z, meta, perm, out);
}

// Round 7
// 110.300 us; speedup vs baseline: 1.5411x; 1.0649x over previous
//
#include <hip/hip_runtime.h>
#include <cstdint>
#include <cstddef>

#define LNUM 8
#define NTOK 8192
#define HDIM 768
#define IDIM 1536

typedef __bf16 bf16x8 __attribute__((ext_vector_type(8)));
typedef float f32x4 __attribute__((ext_vector_type(4)));

__device__ __forceinline__ void gload16(void* lds, const void* gsrc) {
  __builtin_amdgcn_global_load_lds(
      (const __attribute__((address_space(1))) void*)gsrc,
      (__attribute__((address_space(3))) void*)lds, 16, 0, 0);
}

// fast GELU: x * sigmoid(2u), u = 0.79788456*(x + 0.044715 x^3)
__device__ __forceinline__ float gelu_f(float x) {
  float xx = x * x;
  float u = x * __builtin_fmaf(0.0356774081f, xx, 0.7978845608f);
  float t = __builtin_exp2f(-2.8853900817779268f * u);  // e^{-2u}
  return x * __builtin_amdgcn_rcpf(1.0f + t);
}

// meta layout (ints): [0..255] per-block hist (32 blocks x 8 experts)
//                     [256..264] offs, [265..273] tileOffs128
__global__ void hist_kernel(const int* __restrict__ lid, int* __restrict__ meta) {
  __shared__ int c[LNUM];
  if (threadIdx.x < LNUM) c[threadIdx.x] = 0;
  __syncthreads();
  int i = blockIdx.x * 256 + threadIdx.x;
  atomicAdd(&c[lid[i]], 1);
  __syncthreads();
  if (threadIdx.x < LNUM) meta[blockIdx.x * LNUM + threadIdx.x] = c[threadIdx.x];
}

// transpose+convert one 64x64 tile: dst[C][R] (bf16) <- src[R][C] (f32)
__device__ __forceinline__ void tr_cvt_tile(float (*tile)[65], const float* src,
                                            __bf16* dst, int R, int C, int r0,
                                            int c0, int t) {
  int rr = t >> 4, cc = (t & 15) << 2;
  #pragma unroll
  for (int it = 0; it < 4; ++it) {
    float4 v = *(const float4*)&src[(size_t)(r0 + rr + it * 16) * C + c0 + cc];
    tile[rr + it * 16][cc] = v.x;
    tile[rr + it * 16][cc + 1] = v.y;
    tile[rr + it * 16][cc + 2] = v.z;
    tile[rr + it * 16][cc + 3] = v.w;
  }
  __syncthreads();
  int c = t >> 2, rcb = (t & 3) << 3;
  #pragma unroll
  for (int it = 0; it < 2; ++it) {
    int r = rcb + it * 32;
    bf16x8 o;
    #pragma unroll
    for (int j = 0; j < 8; ++j) o[j] = (__bf16)tile[r + j][c];
    *(bf16x8*)&dst[(size_t)(c0 + c) * R + r0 + r] = o;
  }
}

// K2 megaprep: blocks [0,32) scatter (+offs/tiles by block 0),
// [32,3104) conv_z, [3104,5408) w1 transpose, [5408,7712) w2 transpose
#define NB_SC 32
#define NB_CZ 3072
#define NB_W 2304
__global__ __launch_bounds__(256) void megaprep_kernel(
    const int* __restrict__ lid, const float* __restrict__ z,
    const float* __restrict__ w1, const float* __restrict__ w2,
    int* __restrict__ meta, int* __restrict__ perm, bf16x8* __restrict__ zb,
    __bf16* __restrict__ w1t, __bf16* __restrict__ w2t) {
  __shared__ float tile[64][65];
  __shared__ int lcnt[LNUM], lbase[LNUM];
  int bxid = blockIdx.x;
  int tid = threadIdx.x;
  if (bxid < NB_SC) {
    int b = bxid;
    if (tid < LNUM) {
      lcnt[tid] = 0;
      int base = 0;
      for (int ee = 0; ee < tid; ++ee) {
        int s = 0;
        for (int bb = 0; bb < 32; ++bb) s += meta[bb * LNUM + ee];
        base += s;
      }
      for (int bb = 0; bb < b; ++bb) base += meta[bb * LNUM + tid];
      lbase[tid] = base;
    }
    __syncthreads();
    int i = b * 256 + tid;
    int e = lid[i];
    int r = atomicAdd(&lcnt[e], 1);
    perm[lbase[e] + r] = i;
    if (b == 0 && tid == 0) {
      int o = 0, tt = 0;
      for (int e2 = 0; e2 < LNUM; ++e2) {
        int s = 0;
        for (int bb = 0; bb < 32; ++bb) s += meta[bb * LNUM + e2];
        meta[256 + e2] = o;
        meta[265 + e2] = tt;
        o += s;
        tt += (s + 127) >> 7;
      }
      meta[264] = o;
      meta[273] = tt;
    }
  } else if (bxid < NB_SC + NB_CZ) {
    int i = (bxid - NB_SC) * 256 + tid;
    const float4* zf = (const float4*)z;
    float4 a = zf[i * 2], b4 = zf[i * 2 + 1];
    bf16x8 o;
    o[0] = (__bf16)a.x; o[1] = (__bf16)a.y; o[2] = (__bf16)a.z; o[3] = (__bf16)a.w;
    o[4] = (__bf16)b4.x; o[5] = (__bf16)b4.y; o[6] = (__bf16)b4.z; o[7] = (__bf16)b4.w;
    zb[i] = o;
  } else if (bxid < NB_SC + NB_CZ + NB_W) {
    int idx = bxid - (NB_SC + NB_CZ);
    int e = idx / 288, rem = idx % 288;
    int c0 = (rem % 24) * 64, r0 = (rem / 24) * 64;
    tr_cvt_tile(tile, w1 + (size_t)e * HDIM * IDIM, w1t + (size_t)e * HDIM * IDIM,
                HDIM, IDIM, r0, c0, tid);
  } else {
    int idx = bxid - (NB_SC + NB_CZ + NB_W);
    int e = idx / 288, rem = idx % 288;
    int c0 = (rem % 12) * 64, r0 = (rem / 12) * 64;
    tr_cvt_tile(tile, w2 + (size_t)e * HDIM * IDIM, w2t + (size_t)e * HDIM * IDIM,
                IDIM, HDIM, r0, c0, tid);
  }
}

// ---------------- grouped GEMM 1: act = gelu(zb[perm] @ w1t^T + b1) ----------------
// 512 threads (8 waves, 2M x 4N, wave-tile 64x32), 128^2 tile, BK=64 dbuf.
// LDS rows 64 elems; content swizzled: Ls[r][c] = G[r][c ^ ((r&7)<<3)]
__global__ __launch_bounds__(512) void gemm1_kernel(
    const __bf16* __restrict__ zb, const __bf16* __restrict__ w1t,
    const float* __restrict__ b1, const int* __restrict__ meta,
    const int* __restrict__ perm, __bf16* __restrict__ act) {
  __shared__ __bf16 As[2][128 * 64];
  __shared__ __bf16 Bs[2][128 * 64];
  const int* offs = meta + 256;
  const int* tiles = meta + 265;
  int nwg = gridDim.x;
  int bid = blockIdx.x;
  int tileid = (bid & 7) * (nwg >> 3) + (bid >> 3);  // XCD chunking (nwg%8==0)
  int bx = tileid % (IDIM / 128);
  int t = tileid / (IDIM / 128);
  if (t >= tiles[LNUM]) return;
  int e = 0;
  #pragma unroll
  for (int q = 0; q < LNUM - 1; ++q)
    if (t >= tiles[e + 1]) ++e;
  int mtile = t - tiles[e];
  int row0 = offs[e] + (mtile << 7);
  int cntRem = offs[e + 1] - row0;
  if (cntRem > 128) cntRem = 128;
  int n0 = bx << 7;
  int tid = threadIdx.x, lane = tid & 63, wv = tid >> 6;
  int wr = wv >> 2, wc = wv & 3;  // 2M x 4N
  int swz = ((lane & 7) ^ (lane >> 3)) << 3;

  const __bf16* srcA[2];
  const __bf16* srcB[2];
  #pragma unroll
  for (int i = 0; i < 2; ++i) {
    int row = ((wv * 2 + i) << 3) + (lane >> 3);
    int rA = row < cntRem ? row : cntRem - 1;
    int tok = perm[row0 + rA];
    srcA[i] = zb + (size_t)tok * HDIM + swz;
    srcB[i] = w1t + ((size_t)e * IDIM + n0 + row) * HDIM + swz;
  }

  int rswz = (lane & 7) << 3;
  f32x4 acc[4][2] = {};

  #pragma unroll
  for (int i = 0; i < 2; ++i) {
    gload16((char*)As[0] + (((wv * 2 + i)) << 10), srcA[i]);
    gload16((char*)Bs[0] + (((wv * 2 + i)) << 10), srcB[i]);
  }
  __syncthreads();

  int cur = 0;
  for (int kk = 0; kk < HDIM / 64; ++kk) {
    if (kk + 1 < HDIM / 64) {
      #pragma unroll
      for (int i = 0; i < 2; ++i) {
        gload16((char*)As[cur ^ 1] + (((wv * 2 + i)) << 10), srcA[i] + (kk + 1) * 64);
        gload16((char*)Bs[cur ^ 1] + (((wv * 2 + i)) << 10), srcB[i] + (kk + 1) * 64);
      }
    }
    #pragma unroll
    for (int k2 = 0; k2 < 2; ++k2) {
      int kb = (k2 * 32 + ((lane >> 4) << 3)) ^ rswz;
      bf16x8 a[4], b[2];
      #pragma unroll
      for (int mi = 0; mi < 4; ++mi)
        a[mi] = *(const bf16x8*)&As[cur][((wr * 64 + mi * 16 + (lane & 15)) << 6) + kb];
      #pragma unroll
      for (int ni = 0; ni < 2; ++ni)
        b[ni] = *(const bf16x8*)&Bs[cur][((wc * 32 + ni * 16 + (lane & 15)) << 6) + kb];
      #pragma unroll
      for (int mi = 0; mi < 4; ++mi)
        #pragma unroll
        for (int ni = 0; ni < 2; ++ni)
          acc[mi][ni] = __builtin_amdgcn_mfma_f32_16x16x32_bf16(a[mi], b[ni], acc[mi][ni], 0, 0, 0);
    }
    __syncthreads();
    cur ^= 1;
  }

  float bb[2];
  #pragma unroll
  for (int ni = 0; ni < 2; ++ni)
    bb[ni] = b1[e * IDIM + n0 + wc * 32 + ni * 16 + (lane & 15)];

  #pragma unroll
  for (int mi = 0; mi < 4; ++mi) {
    int gr0 = wr * 64 + mi * 16 + ((lane >> 4) << 2);
    #pragma unroll
    for (int r = 0; r < 4; ++r) {
      int g = gr0 + r;
      if (g < cntRem) {
        size_t p = (size_t)(row0 + g);
        #pragma unroll
        for (int ni = 0; ni < 2; ++ni) {
          int col = n0 + wc * 32 + ni * 16 + (lane & 15);
          act[p * IDIM + col] = (__bf16)gelu_f(acc[mi][ni][r] + bb[ni]);
        }
      }
    }
  }
}

// ---------------- grouped GEMM 2: out[tok] = z[tok] + act @ w2t^T + b2 ----------------
__global__ __launch_bounds__(512) void gemm2_kernel(
    const __bf16* __restrict__ act, const __bf16* __restrict__ w2t,
    const float* __restrict__ b2, const float* __restrict__ z,
    const int* __restrict__ meta, const int* __restrict__ perm,
    float* __restrict__ out) {
  __shared__ __bf16 As[2][128 * 64];
  __shared__ __bf16 Bs[2][128 * 64];
  const int* offs = meta + 256;
  const int* tiles = meta + 265;
  int nwg = gridDim.x;
  int bid = blockIdx.x;
  int tileid = (bid & 7) * (nwg >> 3) + (bid >> 3);
  int bx = tileid % (HDIM / 128);
  int t = tileid / (HDIM / 128);
  if (t >= tiles[LNUM]) return;
  int e = 0;
  #pragma unroll
  for (int q = 0; q < LNUM - 1; ++q)
    if (t >= tiles[e + 1]) ++e;
  int mtile = t - tiles[e];
  int row0 = offs[e] + (mtile << 7);
  int cntRem = offs[e + 1] - row0;
  if (cntRem > 128) cntRem = 128;
  int n0 = bx << 7;
  int tid = threadIdx.x, lane = tid & 63, wv = tid >> 6;
  int wr = wv >> 2, wc = wv & 3;
  int swz = ((lane & 7) ^ (lane >> 3)) << 3;

  const __bf16* srcA[2];
  const __bf16* srcB[2];
  #pragma unroll
  for (int i = 0; i < 2; ++i) {
    int row = ((wv * 2 + i) << 3) + (lane >> 3);
    int rA = row < cntRem ? row : cntRem - 1;
    srcA[i] = act + (size_t)(row0 + rA) * IDIM + swz;
    srcB[i] = w2t + ((size_t)e * HDIM + n0 + row) * IDIM + swz;
  }

  int rswz = (lane & 7) << 3;
  f32x4 acc[4][2] = {};

  #pragma unroll
  for (int i = 0; i < 2; ++i) {
    gload16((char*)As[0] + (((wv * 2 + i)) << 10), srcA[i]);
    gload16((char*)Bs[0] + (((wv * 2 + i)) << 10), srcB[i]);
  }
  __syncthreads();

  int cur = 0;
  for (int kk = 0; kk < IDIM / 64; ++kk) {
    if (kk + 1 < IDIM / 64) {
      #pragma unroll
      for (int i = 0; i < 2; ++i) {
        gload16((char*)As[cur ^ 1] + (((wv * 2 + i)) << 10), srcA[i] + (kk + 1) * 64);
        gload16((char*)Bs[cur ^ 1] + (((wv * 2 + i)) << 10), srcB[i] + (kk + 1) * 64);
      }
    }
    #pragma unroll
    for (int k2 = 0; k2 < 2; ++k2) {
      int kb = (k2 * 32 + ((lane >> 4) << 3)) ^ rswz;
      bf16x8 a[4], b[2];
      #pragma unroll
      for (int mi = 0; mi < 4; ++mi)
        a[mi] = *(const bf16x8*)&As[cur][((wr * 64 + mi * 16 + (lane & 15)) << 6) + kb];
      #pragma unroll
      for (int ni = 0; ni < 2; ++ni)
        b[ni] = *(const bf16x8*)&Bs[cur][((wc * 32 + ni * 16 + (lane & 15)) << 6) + kb];
      #pragma unroll
      for (int mi = 0; mi < 4; ++mi)
        #pragma unroll
        for (int ni = 0; ni < 2; ++ni)
          acc[mi][ni] = __builtin_amdgcn_mfma_f32_16x16x32_bf16(a[mi], b[ni], acc[mi][ni], 0, 0, 0);
    }
    __syncthreads();
    cur ^= 1;
  }

  float bb[2];
  #pragma unroll
  for (int ni = 0; ni < 2; ++ni)
    bb[ni] = b2[e * HDIM + n0 + wc * 32 + ni * 16 + (lane & 15)];

  #pragma unroll
  for (int mi = 0; mi < 4; ++mi) {
    int gr0 = wr * 64 + mi * 16 + ((lane >> 4) << 2);
    #pragma unroll
    for (int r = 0; r < 4; ++r) {
      int g = gr0 + r;
      if (g < cntRem) {
        int p = row0 + g;
        int tok = perm[p];
        #pragma unroll
        for (int ni = 0; ni < 2; ++ni) {
          int col = n0 + wc * 32 + ni * 16 + (lane & 15);
          out[(size_t)tok * HDIM + col] =
              z[(size_t)tok * HDIM + col] + acc[mi][ni][r] + bb[ni];
        }
      }
    }
  }
}

extern "C" void kernel_launch(void* const* d_in, const int* in_sizes, int n_in,
                              void* d_out, int out_size, void* d_ws, size_t ws_size,
                              hipStream_t stream) {
  const float* z  = (const float*)d_in[0];
  const int*   lid = (const int*)d_in[1];
  const float* w1 = (const float*)d_in[2];
  const float* b1 = (const float*)d_in[3];
  const float* w2 = (const float*)d_in[4];
  const float* b2 = (const float*)d_in[5];
  float* out = (float*)d_out;
  char* ws = (char*)d_ws;

  int* meta = (int*)ws;                     // 274 ints
  int* perm = (int*)(ws + 2048);            // NTOK ints
  __bf16* zb  = (__bf16*)(ws + 2048 + 32768);
  __bf16* w1t = zb + (size_t)NTOK * HDIM;
  __bf16* w2t = w1t + (size_t)LNUM * HDIM * IDIM;
  __bf16* act = w2t + (size_t)LNUM * HDIM * IDIM;

  hist_kernel<<<NTOK / 256, 256, 0, stream>>>(lid, meta);
  megaprep_kernel<<<NB_SC + NB_CZ + 2 * NB_W, 256, 0, stream>>>(
      lid, z, w1, w2, meta, perm, (bf16x8*)zb, w1t, w2t);
  gemm1_kernel<<<(IDIM / 128) * 72, 512, 0, stream>>>(zb, w1t, b1, meta, perm, act);
  gemm2_kernel<<<(HDIM / 128) * 72, 512, 0, stream>>>(act, w2t, b2, z, meta, perm, out);
}

// Round 8
// 105.966 us; speedup vs baseline: 1.6042x; 1.0409x over previous
//
#include <hip/hip_runtime.h>
#include <cstdint>
#include <cstddef>

#define LNUM 8
#define NTOK 8192
#define HDIM 768
#define IDIM 1536

typedef __bf16 bf16x8 __attribute__((ext_vector_type(8)));
typedef float f32x4 __attribute__((ext_vector_type(4)));

__device__ __forceinline__ void gload16(void* lds, const void* gsrc) {
  __builtin_amdgcn_global_load_lds(
      (const __attribute__((address_space(1))) void*)gsrc,
      (__attribute__((address_space(3))) void*)lds, 16, 0, 0);
}

// fast GELU: x * sigmoid(2u), u = 0.79788456*(x + 0.044715 x^3)
__device__ __forceinline__ float gelu_f(float x) {
  float xx = x * x;
  float u = x * __builtin_fmaf(0.0356774081f, xx, 0.7978845608f);
  float t = __builtin_exp2f(-2.8853900817779268f * u);  // e^{-2u}
  return x * __builtin_amdgcn_rcpf(1.0f + t);
}

// meta ints: [0..8]=offs, [9..17]=tileOffs128
// transpose+convert one 64x64 tile: dst[C][R] (bf16) <- src[R][C] (f32)
__device__ __forceinline__ void tr_cvt_tile(float (*tile)[65], const float* src,
                                            __bf16* dst, int R, int C, int r0,
                                            int c0, int t) {
  int rr = t >> 4, cc = (t & 15) << 2;
  #pragma unroll
  for (int it = 0; it < 4; ++it) {
    float4 v = *(const float4*)&src[(size_t)(r0 + rr + it * 16) * C + c0 + cc];
    tile[rr + it * 16][cc] = v.x;
    tile[rr + it * 16][cc + 1] = v.y;
    tile[rr + it * 16][cc + 2] = v.z;
    tile[rr + it * 16][cc + 3] = v.w;
  }
  __syncthreads();
  int c = t >> 2, rcb = (t & 3) << 3;
  #pragma unroll
  for (int it = 0; it < 2; ++it) {
    int r = rcb + it * 32;
    bf16x8 o;
    #pragma unroll
    for (int j = 0; j < 8; ++j) o[j] = (__bf16)tile[r + j][c];
    *(bf16x8*)&dst[(size_t)(c0 + c) * R + r0 + r] = o;
  }
}

// K1 prep: [0,32) scatter (self-hist; block 0 writes offs/tiles),
// [32,3104) conv_z, [3104,5408) w1 transpose
#define NB_SC 32
#define NB_CZ 3072
#define NB_W 2304
__global__ __launch_bounds__(256) void prep_kernel(
    const int* __restrict__ lid, const float* __restrict__ z,
    const float* __restrict__ w1, int* __restrict__ meta,
    int* __restrict__ perm, bf16x8* __restrict__ zb, __bf16* __restrict__ w1t) {
  __shared__ float tile[64][65];
  int bxid = blockIdx.x;
  int tid = threadIdx.x;
  if (bxid < NB_SC) {
    __shared__ int ctw[4][LNUM], cbw[4][LNUM];
    __shared__ int lcnt[LNUM], lbase[LNUM];
    int b = bxid, wv = tid >> 6;
    if (tid < 32) {
      ctw[tid >> 3][tid & 7] = 0;
      cbw[tid >> 3][tid & 7] = 0;
    }
    if (tid < LNUM) lcnt[tid] = 0;
    __syncthreads();
    int cut = b << 8;
    for (int i = tid; i < NTOK; i += 256) {
      int e = lid[i];
      atomicAdd(&ctw[wv][e], 1);
      if (i < cut) atomicAdd(&cbw[wv][e], 1);
    }
    __syncthreads();
    if (tid < LNUM) {
      int e = tid, o = 0;
      for (int e2 = 0; e2 < LNUM; ++e2) {
        int s = ctw[0][e2] + ctw[1][e2] + ctw[2][e2] + ctw[3][e2];
        if (e2 < e) o += s;
      }
      lbase[e] = o + cbw[0][e] + cbw[1][e] + cbw[2][e] + cbw[3][e];
    }
    if (b == 0 && tid == 0) {
      int o = 0, tt = 0;
      for (int e2 = 0; e2 < LNUM; ++e2) {
        int s = ctw[0][e2] + ctw[1][e2] + ctw[2][e2] + ctw[3][e2];
        meta[e2] = o;
        meta[9 + e2] = tt;
        o += s;
        tt += (s + 127) >> 7;
      }
      meta[8] = o;
      meta[17] = tt;
    }
    __syncthreads();
    int i = (b << 8) + tid;
    int e = lid[i];
    int r = atomicAdd(&lcnt[e], 1);
    perm[lbase[e] + r] = i;
  } else if (bxid < NB_SC + NB_CZ) {
    int i = (bxid - NB_SC) * 256 + tid;
    const float4* zf = (const float4*)z;
    float4 a = zf[i * 2], b4 = zf[i * 2 + 1];
    bf16x8 o;
    o[0] = (__bf16)a.x; o[1] = (__bf16)a.y; o[2] = (__bf16)a.z; o[3] = (__bf16)a.w;
    o[4] = (__bf16)b4.x; o[5] = (__bf16)b4.y; o[6] = (__bf16)b4.z; o[7] = (__bf16)b4.w;
    zb[i] = o;
  } else {
    int idx = bxid - (NB_SC + NB_CZ);
    int e = idx / 288, rem = idx % 288;
    int c0 = (rem % 24) * 64, r0 = (rem / 24) * 64;
    tr_cvt_tile(tile, w1 + (size_t)e * HDIM * IDIM, w1t + (size_t)e * HDIM * IDIM,
                HDIM, IDIM, r0, c0, tid);
  }
}

// ---------------- K2: gemm1 (blocks [0,1728)) + w2 transpose ([1728,4032)) ----
// gemm1: act = gelu(zb[perm] @ w1t^T + b1). Tile 128x64, BK=64, single-buffer,
// 4 waves (2M x 2N, wave-tile 64x32). LDS swizzle Ls[r][c] = G[r][c^((r&7)<<3)].
#define G1NT 24
#define G1GRID (G1NT * 72)
__global__ __launch_bounds__(256) void gemm1_kernel(
    const __bf16* __restrict__ zb, const __bf16* __restrict__ w1t,
    const float* __restrict__ b1, const int* __restrict__ meta,
    const int* __restrict__ perm, __bf16* __restrict__ act,
    const float* __restrict__ w2, __bf16* __restrict__ w2t) {
  __shared__ __align__(16) char smem[24576];
  int bid = blockIdx.x;
  int tid = threadIdx.x;
  if (bid >= G1GRID) {
    // ---- w2 [I][H] -> w2t [H][I] ----
    float (*tile)[65] = (float (*)[65])smem;
    int idx = bid - G1GRID;
    int e = idx / 288, rem = idx % 288;
    int c0 = (rem % 12) * 64, r0 = (rem / 12) * 64;
    tr_cvt_tile(tile, w2 + (size_t)e * HDIM * IDIM, w2t + (size_t)e * HDIM * IDIM,
                IDIM, HDIM, r0, c0, tid);
    return;
  }
  __bf16* As = (__bf16*)smem;              // [128][64]
  __bf16* Bs = (__bf16*)(smem + 16384);    // [64][64]
  const int* offs = meta;
  const int* tiles = meta + 9;
  int tileid = (bid & 7) * (G1GRID >> 3) + (bid >> 3);  // XCD chunking
  int bx = tileid % G1NT;
  int t = tileid / G1NT;
  if (t >= tiles[LNUM]) return;
  int e = 0;
  #pragma unroll
  for (int q = 0; q < LNUM - 1; ++q)
    if (t >= tiles[e + 1]) ++e;
  int mtile = t - tiles[e];
  int row0 = offs[e] + (mtile << 7);
  int cntRem = offs[e + 1] - row0;
  if (cntRem > 128) cntRem = 128;
  int n0 = bx << 6;
  int lane = tid & 63, wv = tid >> 6;
  int wr = wv >> 1, wc = wv & 1;
  int swz = ((lane & 7) ^ (lane >> 3)) << 3;

  const __bf16* srcA[4];
  const __bf16* srcB[2];
  #pragma unroll
  for (int i = 0; i < 4; ++i) {
    int row = ((wv * 4 + i) << 3) + (lane >> 3);
    int rA = row < cntRem ? row : cntRem - 1;
    int tok = perm[row0 + rA];
    srcA[i] = zb + (size_t)tok * HDIM + swz;
  }
  #pragma unroll
  for (int i = 0; i < 2; ++i) {
    int row = ((wv * 2 + i) << 3) + (lane >> 3);
    srcB[i] = w1t + ((size_t)e * IDIM + n0 + row) * HDIM + swz;
  }

  int rswz = (lane & 7) << 3;
  f32x4 acc[4][2] = {};

  for (int kk = 0; kk < HDIM / 64; ++kk) {
    #pragma unroll
    for (int i = 0; i < 4; ++i)
      gload16(As + ((wv * 4 + i) << 9), srcA[i] + kk * 64);
    #pragma unroll
    for (int i = 0; i < 2; ++i)
      gload16(Bs + ((wv * 2 + i) << 9), srcB[i] + kk * 64);
    __syncthreads();
    #pragma unroll
    for (int k2 = 0; k2 < 2; ++k2) {
      int kb = (k2 * 32 + ((lane >> 4) << 3)) ^ rswz;
      bf16x8 a[4], b[2];
      #pragma unroll
      for (int mi = 0; mi < 4; ++mi)
        a[mi] = *(const bf16x8*)&As[((wr * 64 + mi * 16 + (lane & 15)) << 6) + kb];
      #pragma unroll
      for (int ni = 0; ni < 2; ++ni)
        b[ni] = *(const bf16x8*)&Bs[((wc * 32 + ni * 16 + (lane & 15)) << 6) + kb];
      #pragma unroll
      for (int mi = 0; mi < 4; ++mi)
        #pragma unroll
        for (int ni = 0; ni < 2; ++ni)
          acc[mi][ni] = __builtin_amdgcn_mfma_f32_16x16x32_bf16(a[mi], b[ni], acc[mi][ni], 0, 0, 0);
    }
    __syncthreads();
  }

  float bb[2];
  #pragma unroll
  for (int ni = 0; ni < 2; ++ni)
    bb[ni] = b1[e * IDIM + n0 + wc * 32 + ni * 16 + (lane & 15)];

  #pragma unroll
  for (int mi = 0; mi < 4; ++mi) {
    int gr0 = wr * 64 + mi * 16 + ((lane >> 4) << 2);
    #pragma unroll
    for (int r = 0; r < 4; ++r) {
      int g = gr0 + r;
      if (g < cntRem) {
        size_t p = (size_t)(row0 + g);
        #pragma unroll
        for (int ni = 0; ni < 2; ++ni) {
          int col = n0 + wc * 32 + ni * 16 + (lane & 15);
          act[p * IDIM + col] = (__bf16)gelu_f(acc[mi][ni][r] + bb[ni]);
        }
      }
    }
  }
}

// ---------------- K3 gemm2: out[tok] = z[tok] + act @ w2t^T + b2 --------------
// Tile 128x64, BK=64, single-buffer, 4 waves.
#define G2NT 12
#define G2GRID (G2NT * 72)
__global__ __launch_bounds__(256) void gemm2_kernel(
    const __bf16* __restrict__ act, const __bf16* __restrict__ w2t,
    const float* __restrict__ b2, const float* __restrict__ z,
    const int* __restrict__ meta, const int* __restrict__ perm,
    float* __restrict__ out) {
  __shared__ __align__(16) char smem[24576];
  __bf16* As = (__bf16*)smem;
  __bf16* Bs = (__bf16*)(smem + 16384);
  const int* offs = meta;
  const int* tiles = meta + 9;
  int bid = blockIdx.x;
  int tileid = (bid & 7) * (G2GRID >> 3) + (bid >> 3);
  int bx = tileid % G2NT;
  int t = tileid / G2NT;
  if (t >= tiles[LNUM]) return;
  int e = 0;
  #pragma unroll
  for (int q = 0; q < LNUM - 1; ++q)
    if (t >= tiles[e + 1]) ++e;
  int mtile = t - tiles[e];
  int row0 = offs[e] + (mtile << 7);
  int cntRem = offs[e + 1] - row0;
  if (cntRem > 128) cntRem = 128;
  int n0 = bx << 6;
  int tid = threadIdx.x, lane = tid & 63, wv = tid >> 6;
  int wr = wv >> 1, wc = wv & 1;
  int swz = ((lane & 7) ^ (lane >> 3)) << 3;

  const __bf16* srcA[4];
  const __bf16* srcB[2];
  #pragma unroll
  for (int i = 0; i < 4; ++i) {
    int row = ((wv * 4 + i) << 3) + (lane >> 3);
    int rA = row < cntRem ? row : cntRem - 1;
    srcA[i] = act + (size_t)(row0 + rA) * IDIM + swz;
  }
  #pragma unroll
  for (int i = 0; i < 2; ++i) {
    int row = ((wv * 2 + i) << 3) + (lane >> 3);
    srcB[i] = w2t + ((size_t)e * HDIM + n0 + row) * IDIM + swz;
  }

  int rswz = (lane & 7) << 3;
  f32x4 acc[4][2] = {};

  for (int kk = 0; kk < IDIM / 64; ++kk) {
    #pragma unroll
    for (int i = 0; i < 4; ++i)
      gload16(As + ((wv * 4 + i) << 9), srcA[i] + kk * 64);
    #pragma unroll
    for (int i = 0; i < 2; ++i)
      gload16(Bs + ((wv * 2 + i) << 9), srcB[i] + kk * 64);
    __syncthreads();
    #pragma unroll
    for (int k2 = 0; k2 < 2; ++k2) {
      int kb = (k2 * 32 + ((lane >> 4) << 3)) ^ rswz;
      bf16x8 a[4], b[2];
      #pragma unroll
      for (int mi = 0; mi < 4; ++mi)
        a[mi] = *(const bf16x8*)&As[((wr * 64 + mi * 16 + (lane & 15)) << 6) + kb];
      #pragma unroll
      for (int ni = 0; ni < 2; ++ni)
        b[ni] = *(const bf16x8*)&Bs[((wc * 32 + ni * 16 + (lane & 15)) << 6) + kb];
      #pragma unroll
      for (int mi = 0; mi < 4; ++mi)
        #pragma unroll
        for (int ni = 0; ni < 2; ++ni)
          acc[mi][ni] = __builtin_amdgcn_mfma_f32_16x16x32_bf16(a[mi], b[ni], acc[mi][ni], 0, 0, 0);
    }
    __syncthreads();
  }

  float bb[2];
  #pragma unroll
  for (int ni = 0; ni < 2; ++ni)
    bb[ni] = b2[e * HDIM + n0 + wc * 32 + ni * 16 + (lane & 15)];

  #pragma unroll
  for (int mi = 0; mi < 4; ++mi) {
    int gr0 = wr * 64 + mi * 16 + ((lane >> 4) << 2);
    #pragma unroll
    for (int r = 0; r < 4; ++r) {
      int g = gr0 + r;
      if (g < cntRem) {
        int p = row0 + g;
        int tok = perm[p];
        #pragma unroll
        for (int ni = 0; ni < 2; ++ni) {
          int col = n0 + wc * 32 + ni * 16 + (lane & 15);
          out[(size_t)tok * HDIM + col] =
              z[(size_t)tok * HDIM + col] + acc[mi][ni][r] + bb[ni];
        }
      }
    }
  }
}

extern "C" void kernel_launch(void* const* d_in, const int* in_sizes, int n_in,
                              void* d_out, int out_size, void* d_ws, size_t ws_size,
                              hipStream_t stream) {
  const float* z  = (const float*)d_in[0];
  const int*   lid = (const int*)d_in[1];
  const float* w1 = (const float*)d_in[2];
  const float* b1 = (const float*)d_in[3];
  const float* w2 = (const float*)d_in[4];
  const float* b2 = (const float*)d_in[5];
  float* out = (float*)d_out;
  char* ws = (char*)d_ws;

  int* meta = (int*)ws;                     // 18 ints
  int* perm = (int*)(ws + 2048);            // NTOK ints
  __bf16* zb  = (__bf16*)(ws + 2048 + 32768);
  __bf16* w1t = zb + (size_t)NTOK * HDIM;
  __bf16* w2t = w1t + (size_t)LNUM * HDIM * IDIM;
  __bf16* act = w2t + (size_t)LNUM * HDIM * IDIM;

  prep_kernel<<<NB_SC + NB_CZ + NB_W, 256, 0, stream>>>(
      lid, z, w1, meta, perm, (bf16x8*)zb, w1t);
  gemm1_kernel<<<G1GRID + NB_W, 256, 0, stream>>>(zb, w1t, b1, meta, perm, act,
                                                  w2, w2t);
  gemm2_kernel<<<G2GRID, 256, 0, stream>>>(act, w2t, b2, z, meta, perm, out);
}

// Round 9
// 101.538 us; speedup vs baseline: 1.6741x; 1.0436x over previous
//
#include <hip/hip_runtime.h>
#include <cstdint>
#include <cstddef>

#define LNUM 8
#define NTOK 8192
#define HDIM 768
#define IDIM 1536

typedef __bf16 bf16x8 __attribute__((ext_vector_type(8)));
typedef float f32x4 __attribute__((ext_vector_type(4)));

__device__ __forceinline__ void gload16(void* lds, const void* gsrc) {
  __builtin_amdgcn_global_load_lds(
      (const __attribute__((address_space(1))) void*)gsrc,
      (__attribute__((address_space(3))) void*)lds, 16, 0, 0);
}

// fast GELU: x * sigmoid(2u), u = 0.79788456*(x + 0.044715 x^3)
__device__ __forceinline__ float gelu_f(float x) {
  float xx = x * x;
  float u = x * __builtin_fmaf(0.0356774081f, xx, 0.7978845608f);
  float t = __builtin_exp2f(-2.8853900817779268f * u);  // e^{-2u}
  return x * __builtin_amdgcn_rcpf(1.0f + t);
}

// meta ints: [0..8] = expert offsets (prefix sums of counts)
// transpose+convert one 64x64 tile: dst[C][R] (bf16) <- src[R][C] (f32)
__device__ __forceinline__ void tr_cvt_tile(float (*tile)[65], const float* src,
                                            __bf16* dst, int R, int C, int r0,
                                            int c0, int t) {
  int rr = t >> 4, cc = (t & 15) << 2;
  #pragma unroll
  for (int it = 0; it < 4; ++it) {
    float4 v = *(const float4*)&src[(size_t)(r0 + rr + it * 16) * C + c0 + cc];
    tile[rr + it * 16][cc] = v.x;
    tile[rr + it * 16][cc + 1] = v.y;
    tile[rr + it * 16][cc + 2] = v.z;
    tile[rr + it * 16][cc + 3] = v.w;
  }
  __syncthreads();
  int c = t >> 2, rcb = (t & 3) << 3;
  #pragma unroll
  for (int it = 0; it < 2; ++it) {
    int r = rcb + it * 32;
    bf16x8 o;
    #pragma unroll
    for (int j = 0; j < 8; ++j) o[j] = (__bf16)tile[r + j][c];
    *(bf16x8*)&dst[(size_t)(c0 + c) * R + r0 + r] = o;
  }
}

// K1 prep: [0,32) scatter (self-hist; block 0 writes offs),
// [32,3104) conv_z, [3104,5408) w1 transpose
#define NB_SC 32
#define NB_CZ 3072
#define NB_W 2304
__global__ __launch_bounds__(256) void prep_kernel(
    const int* __restrict__ lid, const float* __restrict__ z,
    const float* __restrict__ w1, int* __restrict__ meta,
    int* __restrict__ perm, bf16x8* __restrict__ zb, __bf16* __restrict__ w1t) {
  __shared__ float tile[64][65];
  int bxid = blockIdx.x;
  int tid = threadIdx.x;
  if (bxid < NB_SC) {
    __shared__ int ctw[4][LNUM], cbw[4][LNUM];
    __shared__ int lcnt[LNUM], lbase[LNUM];
    int b = bxid, wv = tid >> 6;
    if (tid < 32) {
      ctw[tid >> 3][tid & 7] = 0;
      cbw[tid >> 3][tid & 7] = 0;
    }
    if (tid < LNUM) lcnt[tid] = 0;
    __syncthreads();
    int cut = b << 8;
    for (int i = tid; i < NTOK; i += 256) {
      int e = lid[i];
      atomicAdd(&ctw[wv][e], 1);
      if (i < cut) atomicAdd(&cbw[wv][e], 1);
    }
    __syncthreads();
    if (tid < LNUM) {
      int e = tid, o = 0;
      for (int e2 = 0; e2 < LNUM; ++e2) {
        int s = ctw[0][e2] + ctw[1][e2] + ctw[2][e2] + ctw[3][e2];
        if (e2 < e) o += s;
      }
      lbase[e] = o + cbw[0][e] + cbw[1][e] + cbw[2][e] + cbw[3][e];
    }
    if (b == 0 && tid == 0) {
      int o = 0;
      for (int e2 = 0; e2 < LNUM; ++e2) {
        int s = ctw[0][e2] + ctw[1][e2] + ctw[2][e2] + ctw[3][e2];
        meta[e2] = o;
        o += s;
      }
      meta[8] = o;
    }
    __syncthreads();
    int i = (b << 8) + tid;
    int e = lid[i];
    int r = atomicAdd(&lcnt[e], 1);
    perm[lbase[e] + r] = i;
  } else if (bxid < NB_SC + NB_CZ) {
    int i = (bxid - NB_SC) * 256 + tid;
    const float4* zf = (const float4*)z;
    float4 a = zf[i * 2], b4 = zf[i * 2 + 1];
    bf16x8 o;
    o[0] = (__bf16)a.x; o[1] = (__bf16)a.y; o[2] = (__bf16)a.z; o[3] = (__bf16)a.w;
    o[4] = (__bf16)b4.x; o[5] = (__bf16)b4.y; o[6] = (__bf16)b4.z; o[7] = (__bf16)b4.w;
    zb[i] = o;
  } else {
    int idx = bxid - (NB_SC + NB_CZ);
    int e = idx / 288, rem = idx % 288;
    int c0 = (rem % 24) * 64, r0 = (rem / 24) * 64;
    tr_cvt_tile(tile, w1 + (size_t)e * HDIM * IDIM, w1t + (size_t)e * HDIM * IDIM,
                HDIM, IDIM, r0, c0, tid);
  }
}

// ---------------- K2: gemm1 (blocks [0,1152)) + w2 transpose ([1152,3456)) ----
// gemm1: act = gelu(zb[perm] @ w1t^T + b1). Tile 128x128, BK=64, single-buffer,
// 4 waves (2M x 2N, wave-tile 64x64). Expert-XCD affinity: e = bid & 7.
// LDS swizzle Ls[r][c] = G[r][c ^ ((r&7)<<3)].
#define G1GRID 1152
__global__ __launch_bounds__(256) void gemm1_kernel(
    const __bf16* __restrict__ zb, const __bf16* __restrict__ w1t,
    const float* __restrict__ b1, const int* __restrict__ meta,
    const int* __restrict__ perm, __bf16* __restrict__ act,
    const float* __restrict__ w2, __bf16* __restrict__ w2t) {
  __shared__ __align__(16) char smem[32768];
  int bid = blockIdx.x;
  int tid = threadIdx.x;
  if (bid >= G1GRID) {
    // ---- w2 [I][H] -> w2t [H][I] ----
    float (*tile)[65] = (float (*)[65])smem;
    int idx = bid - G1GRID;
    int e = idx / 288, rem = idx % 288;
    int c0 = (rem % 12) * 64, r0 = (rem / 12) * 64;
    tr_cvt_tile(tile, w2 + (size_t)e * HDIM * IDIM, w2t + (size_t)e * HDIM * IDIM,
                IDIM, HDIM, r0, c0, tid);
    return;
  }
  __bf16* As = (__bf16*)smem;              // [128][64]
  __bf16* Bs = (__bf16*)(smem + 16384);    // [128][64]
  const int* offs = meta;
  int e = bid & 7;                          // expert == XCD (bid%8 round-robin)
  int r = bid >> 3;                         // 0..143
  int mt = r / 12, nt = r % 12;
  int off0 = offs[e];
  int cnt = offs[e + 1] - off0;
  if ((mt << 7) >= cnt) return;
  int row0 = off0 + (mt << 7);
  int cntRem = cnt - (mt << 7);
  if (cntRem > 128) cntRem = 128;
  int n0 = nt << 7;
  int lane = tid & 63, wv = tid >> 6;
  int wr = wv >> 1, wc = wv & 1;
  int swz = ((lane & 7) ^ (lane >> 3)) << 3;

  const __bf16* srcA[4];
  const __bf16* srcB[4];
  #pragma unroll
  for (int i = 0; i < 4; ++i) {
    int row = ((wv * 4 + i) << 3) + (lane >> 3);
    int rA = row < cntRem ? row : cntRem - 1;
    int tok = perm[row0 + rA];
    srcA[i] = zb + (size_t)tok * HDIM + swz;
    srcB[i] = w1t + ((size_t)e * IDIM + n0 + row) * HDIM + swz;
  }

  int rswz = (lane & 7) << 3;
  f32x4 acc[4][4] = {};

  for (int kk = 0; kk < HDIM / 64; ++kk) {
    #pragma unroll
    for (int i = 0; i < 4; ++i) {
      gload16(As + ((wv * 4 + i) << 9), srcA[i] + kk * 64);
      gload16(Bs + ((wv * 4 + i) << 9), srcB[i] + kk * 64);
    }
    __syncthreads();
    #pragma unroll
    for (int k2 = 0; k2 < 2; ++k2) {
      int kb = (k2 * 32 + ((lane >> 4) << 3)) ^ rswz;
      bf16x8 a[4], b[4];
      #pragma unroll
      for (int mi = 0; mi < 4; ++mi)
        a[mi] = *(const bf16x8*)&As[((wr * 64 + mi * 16 + (lane & 15)) << 6) + kb];
      #pragma unroll
      for (int ni = 0; ni < 4; ++ni)
        b[ni] = *(const bf16x8*)&Bs[((wc * 64 + ni * 16 + (lane & 15)) << 6) + kb];
      #pragma unroll
      for (int mi = 0; mi < 4; ++mi)
        #pragma unroll
        for (int ni = 0; ni < 4; ++ni)
          acc[mi][ni] = __builtin_amdgcn_mfma_f32_16x16x32_bf16(a[mi], b[ni], acc[mi][ni], 0, 0, 0);
    }
    __syncthreads();
  }

  float bb[4];
  #pragma unroll
  for (int ni = 0; ni < 4; ++ni)
    bb[ni] = b1[e * IDIM + n0 + wc * 64 + ni * 16 + (lane & 15)];

  #pragma unroll
  for (int mi = 0; mi < 4; ++mi) {
    int gr0 = wr * 64 + mi * 16 + ((lane >> 4) << 2);
    #pragma unroll
    for (int r2 = 0; r2 < 4; ++r2) {
      int g = gr0 + r2;
      if (g < cntRem) {
        size_t p = (size_t)(row0 + g);
        #pragma unroll
        for (int ni = 0; ni < 4; ++ni) {
          int col = n0 + wc * 64 + ni * 16 + (lane & 15);
          act[p * IDIM + col] = (__bf16)gelu_f(acc[mi][ni][r2] + bb[ni]);
        }
      }
    }
  }
}

// ---------------- K3 gemm2: out[tok] = z[tok] + act @ w2t^T + b2 --------------
// Tile 128x64, BK=64, single-buffer, 4 waves. Expert-XCD affinity: e = bid & 7.
#define G2GRID 1152
__global__ __launch_bounds__(256) void gemm2_kernel(
    const __bf16* __restrict__ act, const __bf16* __restrict__ w2t,
    const float* __restrict__ b2, const float* __restrict__ z,
    const int* __restrict__ meta, const int* __restrict__ perm,
    float* __restrict__ out) {
  __shared__ __align__(16) char smem[24576];
  __bf16* As = (__bf16*)smem;              // [128][64]
  __bf16* Bs = (__bf16*)(smem + 16384);    // [64][64]
  const int* offs = meta;
  int bid = blockIdx.x;
  int e = bid & 7;
  int r = bid >> 3;                         // 0..143
  int mt = r / 12, nt = r % 12;
  int off0 = offs[e];
  int cnt = offs[e + 1] - off0;
  if ((mt << 7) >= cnt) return;
  int row0 = off0 + (mt << 7);
  int cntRem = cnt - (mt << 7);
  if (cntRem > 128) cntRem = 128;
  int n0 = nt << 6;
  int tid = threadIdx.x, lane = tid & 63, wv = tid >> 6;
  int wr = wv >> 1, wc = wv & 1;
  int swz = ((lane & 7) ^ (lane >> 3)) << 3;

  const __bf16* srcA[4];
  const __bf16* srcB[2];
  #pragma unroll
  for (int i = 0; i < 4; ++i) {
    int row = ((wv * 4 + i) << 3) + (lane >> 3);
    int rA = row < cntRem ? row : cntRem - 1;
    srcA[i] = act + (size_t)(row0 + rA) * IDIM + swz;
  }
  #pragma unroll
  for (int i = 0; i < 2; ++i) {
    int row = ((wv * 2 + i) << 3) + (lane >> 3);
    srcB[i] = w2t + ((size_t)e * HDIM + n0 + row) * IDIM + swz;
  }

  int rswz = (lane & 7) << 3;
  f32x4 acc[4][2] = {};

  for (int kk = 0; kk < IDIM / 64; ++kk) {
    #pragma unroll
    for (int i = 0; i < 4; ++i)
      gload16(As + ((wv * 4 + i) << 9), srcA[i] + kk * 64);
    #pragma unroll
    for (int i = 0; i < 2; ++i)
      gload16(Bs + ((wv * 2 + i) << 9), srcB[i] + kk * 64);
    __syncthreads();
    #pragma unroll
    for (int k2 = 0; k2 < 2; ++k2) {
      int kb = (k2 * 32 + ((lane >> 4) << 3)) ^ rswz;
      bf16x8 a[4], b[2];
      #pragma unroll
      for (int mi = 0; mi < 4; ++mi)
        a[mi] = *(const bf16x8*)&As[((wr * 64 + mi * 16 + (lane & 15)) << 6) + kb];
      #pragma unroll
      for (int ni = 0; ni < 2; ++ni)
        b[ni] = *(const bf16x8*)&Bs[((wc * 32 + ni * 16 + (lane & 15)) << 6) + kb];
      #pragma unroll
      for (int mi = 0; mi < 4; ++mi)
        #pragma unroll
        for (int ni = 0; ni < 2; ++ni)
          acc[mi][ni] = __builtin_amdgcn_mfma_f32_16x16x32_bf16(a[mi], b[ni], acc[mi][ni], 0, 0, 0);
    }
    __syncthreads();
  }

  float bb[2];
  #pragma unroll
  for (int ni = 0; ni < 2; ++ni)
    bb[ni] = b2[e * HDIM + n0 + wc * 32 + ni * 16 + (lane & 15)];

  #pragma unroll
  for (int mi = 0; mi < 4; ++mi) {
    int gr0 = wr * 64 + mi * 16 + ((lane >> 4) << 2);
    #pragma unroll
    for (int r2 = 0; r2 < 4; ++r2) {
      int g = gr0 + r2;
      if (g < cntRem) {
        int p = row0 + g;
        int tok = perm[p];
        #pragma unroll
        for (int ni = 0; ni < 2; ++ni) {
          int col = n0 + wc * 32 + ni * 16 + (lane & 15);
          out[(size_t)tok * HDIM + col] =
              z[(size_t)tok * HDIM + col] + acc[mi][ni][r2] + bb[ni];
        }
      }
    }
  }
}

extern "C" void kernel_launch(void* const* d_in, const int* in_sizes, int n_in,
                              void* d_out, int out_size, void* d_ws, size_t ws_size,
                              hipStream_t stream) {
  const float* z  = (const float*)d_in[0];
  const int*   lid = (const int*)d_in[1];
  const float* w1 = (const float*)d_in[2];
  const float* b1 = (const float*)d_in[3];
  const float* w2 = (const float*)d_in[4];
  const float* b2 = (const float*)d_in[5];
  float* out = (float*)d_out;
  char* ws = (char*)d_ws;

  int* meta = (int*)ws;                     // 9 ints
  int* perm = (int*)(ws + 2048);            // NTOK ints
  __bf16* zb  = (__bf16*)(ws + 2048 + 32768);
  __bf16* w1t = zb + (size_t)NTOK * HDIM;
  __bf16* w2t = w1t + (size_t)LNUM * HDIM * IDIM;
  __bf16* act = w2t + (size_t)LNUM * HDIM * IDIM;

  prep_kernel<<<NB_SC + NB_CZ + NB_W, 256, 0, stream>>>(
      lid, z, w1, meta, perm, (bf16x8*)zb, w1t);
  gemm1_kernel<<<G1GRID + NB_W, 256, 0, stream>>>(zb, w1t, b1, meta, perm, act,
                                                  w2, w2t);
  gemm2_kernel<<<G2GRID, 256, 0, stream>>>(act, w2t, b2, z, meta, perm, out);
}

// Round 10
// 98.873 us; speedup vs baseline: 1.7192x; 1.0270x over previous
//
#include <hip/hip_runtime.h>
#include <cstdint>
#include <cstddef>

#define LNUM 8
#define NTOK 8192
#define HDIM 768
#define IDIM 1536

typedef __bf16 bf16x8 __attribute__((ext_vector_type(8)));
typedef float f32x4 __attribute__((ext_vector_type(4)));

__device__ __forceinline__ void gload16(void* lds, const void* gsrc) {
  __builtin_amdgcn_global_load_lds(
      (const __attribute__((address_space(1))) void*)gsrc,
      (__attribute__((address_space(3))) void*)lds, 16, 0, 0);
}

// fast GELU: x * sigmoid(2u), u = 0.79788456*(x + 0.044715 x^3)
__device__ __forceinline__ float gelu_f(float x) {
  float xx = x * x;
  float u = x * __builtin_fmaf(0.0356774081f, xx, 0.7978845608f);
  float t = __builtin_exp2f(-2.8853900817779268f * u);  // e^{-2u}
  return x * __builtin_amdgcn_rcpf(1.0f + t);
}

// meta ints: [0..8] = expert offsets
// transpose+convert one 64x64 tile: dst[C][R] (bf16) <- src[R][C] (f32)
__device__ __forceinline__ void tr_cvt_tile(float (*tile)[65], const float* src,
                                            __bf16* dst, int R, int C, int r0,
                                            int c0, int t) {
  int rr = t >> 4, cc = (t & 15) << 2;
  #pragma unroll
  for (int it = 0; it < 4; ++it) {
    float4 v = *(const float4*)&src[(size_t)(r0 + rr + it * 16) * C + c0 + cc];
    tile[rr + it * 16][cc] = v.x;
    tile[rr + it * 16][cc + 1] = v.y;
    tile[rr + it * 16][cc + 2] = v.z;
    tile[rr + it * 16][cc + 3] = v.w;
  }
  __syncthreads();
  int c = t >> 2, rcb = (t & 3) << 3;
  #pragma unroll
  for (int it = 0; it < 2; ++it) {
    int r = rcb + it * 32;
    bf16x8 o;
    #pragma unroll
    for (int j = 0; j < 8; ++j) o[j] = (__bf16)tile[r + j][c];
    *(bf16x8*)&dst[(size_t)(c0 + c) * R + r0 + r] = o;
  }
}

// K1 prep: [0,32) scatter (self-hist; block 0 writes offs),
// [32,3104) conv_z, [3104,5408) w1 transpose (XCD-affine: e = idx&7)
#define NB_SC 32
#define NB_CZ 3072
#define NB_W 2304
__global__ __launch_bounds__(256) void prep_kernel(
    const int* __restrict__ lid, const float* __restrict__ z,
    const float* __restrict__ w1, int* __restrict__ meta,
    int* __restrict__ perm, bf16x8* __restrict__ zb, __bf16* __restrict__ w1t) {
  __shared__ float tile[64][65];
  int bxid = blockIdx.x;
  int tid = threadIdx.x;
  if (bxid < NB_SC) {
    __shared__ int ctw[4][LNUM], cbw[4][LNUM];
    __shared__ int lcnt[LNUM], lbase[LNUM];
    int b = bxid, wv = tid >> 6;
    if (tid < 32) {
      ctw[tid >> 3][tid & 7] = 0;
      cbw[tid >> 3][tid & 7] = 0;
    }
    if (tid < LNUM) lcnt[tid] = 0;
    __syncthreads();
    int cut = b << 8;
    for (int i = tid; i < NTOK; i += 256) {
      int e = lid[i];
      atomicAdd(&ctw[wv][e], 1);
      if (i < cut) atomicAdd(&cbw[wv][e], 1);
    }
    __syncthreads();
    if (tid < LNUM) {
      int e = tid, o = 0;
      for (int e2 = 0; e2 < LNUM; ++e2) {
        int s = ctw[0][e2] + ctw[1][e2] + ctw[2][e2] + ctw[3][e2];
        if (e2 < e) o += s;
      }
      lbase[e] = o + cbw[0][e] + cbw[1][e] + cbw[2][e] + cbw[3][e];
    }
    if (b == 0 && tid == 0) {
      int o = 0;
      for (int e2 = 0; e2 < LNUM; ++e2) {
        int s = ctw[0][e2] + ctw[1][e2] + ctw[2][e2] + ctw[3][e2];
        meta[e2] = o;
        o += s;
      }
      meta[8] = o;
    }
    __syncthreads();
    int i = (b << 8) + tid;
    int e = lid[i];
    int r = atomicAdd(&lcnt[e], 1);
    perm[lbase[e] + r] = i;
  } else if (bxid < NB_SC + NB_CZ) {
    int i = (bxid - NB_SC) * 256 + tid;
    const float4* zf = (const float4*)z;
    float4 a = zf[i * 2], b4 = zf[i * 2 + 1];
    bf16x8 o;
    o[0] = (__bf16)a.x; o[1] = (__bf16)a.y; o[2] = (__bf16)a.z; o[3] = (__bf16)a.w;
    o[4] = (__bf16)b4.x; o[5] = (__bf16)b4.y; o[6] = (__bf16)b4.z; o[7] = (__bf16)b4.w;
    zb[i] = o;
  } else {
    // base 3104 %8==0 -> XCD = idx&7 = expert (panel lands in local L2)
    int idx = bxid - (NB_SC + NB_CZ);
    int e = idx & 7, rem = idx >> 3;
    int c0 = (rem % 24) * 64, r0 = (rem / 24) * 64;
    tr_cvt_tile(tile, w1 + (size_t)e * HDIM * IDIM, w1t + (size_t)e * HDIM * IDIM,
                HDIM, IDIM, r0, c0, tid);
  }
}

// ---------------- K2: gemm1 (blocks [0,1152)) + w2 transpose ([1152,3456)) ----
// gemm1: act = gelu(zb[perm] @ w1t^T + b1). Tile 128x128, BK=64, single-buffer,
// 8 waves (2M x 4N, wave-tile 64x32). Expert-XCD affinity: e = bid & 7.
// LDS swizzle Ls[r][c] = G[r][c ^ ((r&7)<<3)].
#define G1GRID 1152
__global__ __launch_bounds__(512) void gemm1_kernel(
    const __bf16* __restrict__ zb, const __bf16* __restrict__ w1t,
    const float* __restrict__ b1, const int* __restrict__ meta,
    const int* __restrict__ perm, __bf16* __restrict__ act,
    const float* __restrict__ w2, __bf16* __restrict__ w2t) {
  __shared__ __align__(16) char smem[32768];
  int bid = blockIdx.x;
  int tid = threadIdx.x;
  if (bid >= G1GRID) {
    // ---- w2 [I][H] -> w2t [H][I], XCD-affine (1152%8==0 -> idx&7 = XCD) ----
    if (tid >= 256) return;
    float (*tile)[65] = (float (*)[65])smem;
    int idx = bid - G1GRID;
    int e = idx & 7, rem = idx >> 3;
    int c0 = (rem % 12) * 64, r0 = (rem / 12) * 64;
    tr_cvt_tile(tile, w2 + (size_t)e * HDIM * IDIM, w2t + (size_t)e * HDIM * IDIM,
                IDIM, HDIM, r0, c0, tid);
    return;
  }
  __bf16* As = (__bf16*)smem;              // [128][64]
  __bf16* Bs = (__bf16*)(smem + 16384);    // [128][64]
  const int* offs = meta;
  int e = bid & 7;                          // expert == XCD
  int r = bid >> 3;                         // 0..143
  int mt = r / 12, nt = r % 12;
  int off0 = offs[e];
  int cnt = offs[e + 1] - off0;
  if ((mt << 7) >= cnt) return;
  int row0 = off0 + (mt << 7);
  int cntRem = cnt - (mt << 7);
  if (cntRem > 128) cntRem = 128;
  int n0 = nt << 7;
  int lane = tid & 63, wv = tid >> 6;
  int wr = wv >> 2, wc = wv & 3;            // 2M x 4N
  int swz = ((lane & 7) ^ (lane >> 3)) << 3;

  const __bf16* srcA[2];
  const __bf16* srcB[2];
  #pragma unroll
  for (int i = 0; i < 2; ++i) {
    int row = ((wv * 2 + i) << 3) + (lane >> 3);
    int rA = row < cntRem ? row : cntRem - 1;
    int tok = perm[row0 + rA];
    srcA[i] = zb + (size_t)tok * HDIM + swz;
    srcB[i] = w1t + ((size_t)e * IDIM + n0 + row) * HDIM + swz;
  }

  int rswz = (lane & 7) << 3;
  f32x4 acc[4][2] = {};

  for (int kk = 0; kk < HDIM / 64; ++kk) {
    #pragma unroll
    for (int i = 0; i < 2; ++i) {
      gload16(As + ((wv * 2 + i) << 9), srcA[i] + kk * 64);
      gload16(Bs + ((wv * 2 + i) << 9), srcB[i] + kk * 64);
    }
    __syncthreads();
    #pragma unroll
    for (int k2 = 0; k2 < 2; ++k2) {
      int kb = (k2 * 32 + ((lane >> 4) << 3)) ^ rswz;
      bf16x8 a[4], b[2];
      #pragma unroll
      for (int mi = 0; mi < 4; ++mi)
        a[mi] = *(const bf16x8*)&As[((wr * 64 + mi * 16 + (lane & 15)) << 6) + kb];
      #pragma unroll
      for (int ni = 0; ni < 2; ++ni)
        b[ni] = *(const bf16x8*)&Bs[((wc * 32 + ni * 16 + (lane & 15)) << 6) + kb];
      #pragma unroll
      for (int mi = 0; mi < 4; ++mi)
        #pragma unroll
        for (int ni = 0; ni < 2; ++ni)
          acc[mi][ni] = __builtin_amdgcn_mfma_f32_16x16x32_bf16(a[mi], b[ni], acc[mi][ni], 0, 0, 0);
    }
    __syncthreads();
  }

  float bb[2];
  #pragma unroll
  for (int ni = 0; ni < 2; ++ni)
    bb[ni] = b1[e * IDIM + n0 + wc * 32 + ni * 16 + (lane & 15)];

  #pragma unroll
  for (int mi = 0; mi < 4; ++mi) {
    int gr0 = wr * 64 + mi * 16 + ((lane >> 4) << 2);
    #pragma unroll
    for (int r2 = 0; r2 < 4; ++r2) {
      int g = gr0 + r2;
      if (g < cntRem) {
        size_t p = (size_t)(row0 + g);
        #pragma unroll
        for (int ni = 0; ni < 2; ++ni) {
          int col = n0 + wc * 32 + ni * 16 + (lane & 15);
          act[p * IDIM + col] = (__bf16)gelu_f(acc[mi][ni][r2] + bb[ni]);
        }
      }
    }
  }
}

// ---------------- K3 gemm2: out[tok] = z[tok] + act @ w2t^T + b2 --------------
// Tile 128x128, BK=64, single-buffer, 8 waves. Expert-XCD affinity: e = bid&7.
#define G2GRID 576
__global__ __launch_bounds__(512) void gemm2_kernel(
    const __bf16* __restrict__ act, const __bf16* __restrict__ w2t,
    const float* __restrict__ b2, const float* __restrict__ z,
    const int* __restrict__ meta, const int* __restrict__ perm,
    float* __restrict__ out) {
  __shared__ __align__(16) char smem[32768];
  __bf16* As = (__bf16*)smem;              // [128][64]
  __bf16* Bs = (__bf16*)(smem + 16384);    // [128][64]
  const int* offs = meta;
  int bid = blockIdx.x;
  int e = bid & 7;
  int r = bid >> 3;                         // 0..71
  int mt = r / 6, nt = r % 6;
  int off0 = offs[e];
  int cnt = offs[e + 1] - off0;
  if ((mt << 7) >= cnt) return;
  int row0 = off0 + (mt << 7);
  int cntRem = cnt - (mt << 7);
  if (cntRem > 128) cntRem = 128;
  int n0 = nt << 7;
  int tid = threadIdx.x, lane = tid & 63, wv = tid >> 6;
  int wr = wv >> 2, wc = wv & 3;
  int swz = ((lane & 7) ^ (lane >> 3)) << 3;

  const __bf16* srcA[2];
  const __bf16* srcB[2];
  #pragma unroll
  for (int i = 0; i < 2; ++i) {
    int row = ((wv * 2 + i) << 3) + (lane >> 3);
    int rA = row < cntRem ? row : cntRem - 1;
    srcA[i] = act + (size_t)(row0 + rA) * IDIM + swz;
    srcB[i] = w2t + ((size_t)e * HDIM + n0 + row) * IDIM + swz;
  }

  int rswz = (lane & 7) << 3;
  f32x4 acc[4][2] = {};

  for (int kk = 0; kk < IDIM / 64; ++kk) {
    #pragma unroll
    for (int i = 0; i < 2; ++i) {
      gload16(As + ((wv * 2 + i) << 9), srcA[i] + kk * 64);
      gload16(Bs + ((wv * 2 + i) << 9), srcB[i] + kk * 64);
    }
    __syncthreads();
    #pragma unroll
    for (int k2 = 0; k2 < 2; ++k2) {
      int kb = (k2 * 32 + ((lane >> 4) << 3)) ^ rswz;
      bf16x8 a[4], b[2];
      #pragma unroll
      for (int mi = 0; mi < 4; ++mi)
        a[mi] = *(const bf16x8*)&As[((wr * 64 + mi * 16 + (lane & 15)) << 6) + kb];
      #pragma unroll
      for (int ni = 0; ni < 2; ++ni)
        b[ni] = *(const bf16x8*)&Bs[((wc * 32 + ni * 16 + (lane & 15)) << 6) + kb];
      #pragma unroll
      for (int mi = 0; mi < 4; ++mi)
        #pragma unroll
        for (int ni = 0; ni < 2; ++ni)
          acc[mi][ni] = __builtin_amdgcn_mfma_f32_16x16x32_bf16(a[mi], b[ni], acc[mi][ni], 0, 0, 0);
    }
    __syncthreads();
  }

  float bb[2];
  #pragma unroll
  for (int ni = 0; ni < 2; ++ni)
    bb[ni] = b2[e * HDIM + n0 + wc * 32 + ni * 16 + (lane & 15)];

  #pragma unroll
  for (int mi = 0; mi < 4; ++mi) {
    int gr0 = wr * 64 + mi * 16 + ((lane >> 4) << 2);
    #pragma unroll
    for (int r2 = 0; r2 < 4; ++r2) {
      int g = gr0 + r2;
      if (g < cntRem) {
        int p = row0 + g;
        int tok = perm[p];
        #pragma unroll
        for (int ni = 0; ni < 2; ++ni) {
          int col = n0 + wc * 32 + ni * 16 + (lane & 15);
          out[(size_t)tok * HDIM + col] =
              z[(size_t)tok * HDIM + col] + acc[mi][ni][r2] + bb[ni];
        }
      }
    }
  }
}

extern "C" void kernel_launch(void* const* d_in, const int* in_sizes, int n_in,
                              void* d_out, int out_size, void* d_ws, size_t ws_size,
                              hipStream_t stream) {
  const float* z  = (const float*)d_in[0];
  const int*   lid = (const int*)d_in[1];
  const float* w1 = (const float*)d_in[2];
  const float* b1 = (const float*)d_in[3];
  const float* w2 = (const float*)d_in[4];
  const float* b2 = (const float*)d_in[5];
  float* out = (float*)d_out;
  char* ws = (char*)d_ws;

  int* meta = (int*)ws;                     // 9 ints
  int* perm = (int*)(ws + 2048);            // NTOK ints
  __bf16* zb  = (__bf16*)(ws + 2048 + 32768);
  __bf16* w1t = zb + (size_t)NTOK * HDIM;
  __bf16* w2t = w1t + (size_t)LNUM * HDIM * IDIM;
  __bf16* act = w2t + (size_t)LNUM * HDIM * IDIM;

  prep_kernel<<<NB_SC + NB_CZ + NB_W, 256, 0, stream>>>(
      lid, z, w1, meta, perm, (bf16x8*)zb, w1t);
  gemm1_kernel<<<G1GRID + NB_W, 512, 0, stream>>>(zb, w1t, b1, meta, perm, act,
                                                  w2, w2t);
  gemm2_kernel<<<G2GRID, 512, 0, stream>>>(act, w2t, b2, z, meta, perm, out);
}

// Round 11
// 89.947 us; speedup vs baseline: 1.8898x; 1.0992x over previous
//
#include <hip/hip_runtime.h>
#include <cstdint>
#include <cstddef>

#define LNUM 8
#define NTOK 8192
#define HDIM 768
#define IDIM 1536

typedef __bf16 bf16x8 __attribute__((ext_vector_type(8)));
typedef float f32x4 __attribute__((ext_vector_type(4)));

__device__ __forceinline__ void gload16(void* lds, const void* gsrc) {
  __builtin_amdgcn_global_load_lds(
      (const __attribute__((address_space(1))) void*)gsrc,
      (__attribute__((address_space(3))) void*)lds, 16, 0, 0);
}

// fast GELU: x * sigmoid(2u), u = 0.79788456*(x + 0.044715 x^3)
__device__ __forceinline__ float gelu_f(float x) {
  float xx = x * x;
  float u = x * __builtin_fmaf(0.0356774081f, xx, 0.7978845608f);
  float t = __builtin_exp2f(-2.8853900817779268f * u);  // e^{-2u}
  return x * __builtin_amdgcn_rcpf(1.0f + t);
}

// meta ints: [0..8] = expert offsets
// transpose+convert one 64x64 tile: dst[C][R] (bf16) <- src[R][C] (f32)
__device__ __forceinline__ void tr_cvt_tile(float (*tile)[65], const float* src,
                                            __bf16* dst, int R, int C, int r0,
                                            int c0, int t) {
  int rr = t >> 4, cc = (t & 15) << 2;
  #pragma unroll
  for (int it = 0; it < 4; ++it) {
    float4 v = *(const float4*)&src[(size_t)(r0 + rr + it * 16) * C + c0 + cc];
    tile[rr + it * 16][cc] = v.x;
    tile[rr + it * 16][cc + 1] = v.y;
    tile[rr + it * 16][cc + 2] = v.z;
    tile[rr + it * 16][cc + 3] = v.w;
  }
  __syncthreads();
  int c = t >> 2, rcb = (t & 3) << 3;
  #pragma unroll
  for (int it = 0; it < 2; ++it) {
    int r = rcb + it * 32;
    bf16x8 o;
    #pragma unroll
    for (int j = 0; j < 8; ++j) o[j] = (__bf16)tile[r + j][c];
    *(bf16x8*)&dst[(size_t)(c0 + c) * R + r0 + r] = o;
  }
}

// K1 prep: [0,32) scatter (self-hist; block 0 writes offs),
// [32,3104) conv_z, [3104,5408) w1 transpose (XCD-affine: e = idx&7)
#define NB_SC 32
#define NB_CZ 3072
#define NB_W 2304
__global__ __launch_bounds__(256) void prep_kernel(
    const int* __restrict__ lid, const float* __restrict__ z,
    const float* __restrict__ w1, int* __restrict__ meta,
    int* __restrict__ perm, bf16x8* __restrict__ zb, __bf16* __restrict__ w1t) {
  __shared__ float tile[64][65];
  int bxid = blockIdx.x;
  int tid = threadIdx.x;
  if (bxid < NB_SC) {
    __shared__ int ctw[4][LNUM], cbw[4][LNUM];
    __shared__ int lcnt[LNUM], lbase[LNUM];
    int b = bxid, wv = tid >> 6;
    if (tid < 32) {
      ctw[tid >> 3][tid & 7] = 0;
      cbw[tid >> 3][tid & 7] = 0;
    }
    if (tid < LNUM) lcnt[tid] = 0;
    __syncthreads();
    int cut = b << 8;
    for (int i = tid; i < NTOK; i += 256) {
      int e = lid[i];
      atomicAdd(&ctw[wv][e], 1);
      if (i < cut) atomicAdd(&cbw[wv][e], 1);
    }
    __syncthreads();
    if (tid < LNUM) {
      int e = tid, o = 0;
      for (int e2 = 0; e2 < LNUM; ++e2) {
        int s = ctw[0][e2] + ctw[1][e2] + ctw[2][e2] + ctw[3][e2];
        if (e2 < e) o += s;
      }
      lbase[e] = o + cbw[0][e] + cbw[1][e] + cbw[2][e] + cbw[3][e];
    }
    if (b == 0 && tid == 0) {
      int o = 0;
      for (int e2 = 0; e2 < LNUM; ++e2) {
        int s = ctw[0][e2] + ctw[1][e2] + ctw[2][e2] + ctw[3][e2];
        meta[e2] = o;
        o += s;
      }
      meta[8] = o;
    }
    __syncthreads();
    int i = (b << 8) + tid;
    int e = lid[i];
    int r = atomicAdd(&lcnt[e], 1);
    perm[lbase[e] + r] = i;
  } else if (bxid < NB_SC + NB_CZ) {
    int i = (bxid - NB_SC) * 256 + tid;
    const float4* zf = (const float4*)z;
    float4 a = zf[i * 2], b4 = zf[i * 2 + 1];
    bf16x8 o;
    o[0] = (__bf16)a.x; o[1] = (__bf16)a.y; o[2] = (__bf16)a.z; o[3] = (__bf16)a.w;
    o[4] = (__bf16)b4.x; o[5] = (__bf16)b4.y; o[6] = (__bf16)b4.z; o[7] = (__bf16)b4.w;
    zb[i] = o;
  } else {
    int idx = bxid - (NB_SC + NB_CZ);
    int e = idx & 7, rem = idx >> 3;
    int c0 = (rem % 24) * 64, r0 = (rem / 24) * 64;
    tr_cvt_tile(tile, w1 + (size_t)e * HDIM * IDIM, w1t + (size_t)e * HDIM * IDIM,
                HDIM, IDIM, r0, c0, tid);
  }
}

// ---------------- K2: gemm1 (blocks [0,576)) + w2 transpose ([576,2880)) ----
// gemm1: act = gelu(zb[perm] @ w1t^T + b1). Tile 128M x 256N, BK=64,
// single-buffer, 8 waves (2M x 4N, wave-tile 64x64). Expert-XCD: e = bid & 7.
// LDS swizzle Ls[r][c] = G[r][c ^ ((r&7)<<3)].
#define G1GRID 576
__global__ __launch_bounds__(512) void gemm1_kernel(
    const __bf16* __restrict__ zb, const __bf16* __restrict__ w1t,
    const float* __restrict__ b1, const int* __restrict__ meta,
    const int* __restrict__ perm, __bf16* __restrict__ act,
    const float* __restrict__ w2, __bf16* __restrict__ w2t) {
  __shared__ __align__(16) char smem[49152];
  int bid = blockIdx.x;
  int tid = threadIdx.x;
  if (bid >= G1GRID) {
    // ---- w2 [I][H] -> w2t [H][I], XCD-affine (576%8==0 -> idx&7 = XCD) ----
    if (tid >= 256) return;
    float (*tile)[65] = (float (*)[65])smem;
    int idx = bid - G1GRID;
    int e = idx & 7, rem = idx >> 3;
    int c0 = (rem % 12) * 64, r0 = (rem / 12) * 64;
    tr_cvt_tile(tile, w2 + (size_t)e * HDIM * IDIM, w2t + (size_t)e * HDIM * IDIM,
                IDIM, HDIM, r0, c0, tid);
    return;
  }
  __bf16* As = (__bf16*)smem;              // [128][64]
  __bf16* Bs = (__bf16*)(smem + 16384);    // [256][64]
  const int* offs = meta;
  int e = bid & 7;                          // expert == XCD
  int r = bid >> 3;                         // 0..71
  int mt = r / 6, nt = r % 6;
  int off0 = offs[e];
  int cnt = offs[e + 1] - off0;
  if ((mt << 7) >= cnt) return;
  int row0 = off0 + (mt << 7);
  int cntRem = cnt - (mt << 7);
  if (cntRem > 128) cntRem = 128;
  int n0 = nt << 8;
  int lane = tid & 63, wv = tid >> 6;
  int wr = wv >> 2, wc = wv & 3;            // 2M x 4N
  int swz = ((lane & 7) ^ (lane >> 3)) << 3;

  const __bf16* srcA[2];
  const __bf16* srcB[4];
  #pragma unroll
  for (int i = 0; i < 2; ++i) {
    int row = ((wv * 2 + i) << 3) + (lane >> 3);   // 16 A-rows per wave
    int rA = row < cntRem ? row : cntRem - 1;
    int tok = perm[row0 + rA];
    srcA[i] = zb + (size_t)tok * HDIM + swz;
  }
  #pragma unroll
  for (int i = 0; i < 4; ++i) {
    int row = ((wv * 4 + i) << 3) + (lane >> 3);   // 32 B-rows per wave
    srcB[i] = w1t + ((size_t)e * IDIM + n0 + row) * HDIM + swz;
  }

  int rswz = (lane & 7) << 3;
  f32x4 acc[4][4] = {};

  for (int kk = 0; kk < HDIM / 64; ++kk) {
    #pragma unroll
    for (int i = 0; i < 2; ++i)
      gload16(As + ((wv * 2 + i) << 9), srcA[i] + kk * 64);
    #pragma unroll
    for (int i = 0; i < 4; ++i)
      gload16(Bs + ((wv * 4 + i) << 9), srcB[i] + kk * 64);
    __syncthreads();
    #pragma unroll
    for (int k2 = 0; k2 < 2; ++k2) {
      int kb = (k2 * 32 + ((lane >> 4) << 3)) ^ rswz;
      bf16x8 a[4], b[4];
      #pragma unroll
      for (int mi = 0; mi < 4; ++mi)
        a[mi] = *(const bf16x8*)&As[((wr * 64 + mi * 16 + (lane & 15)) << 6) + kb];
      #pragma unroll
      for (int ni = 0; ni < 4; ++ni)
        b[ni] = *(const bf16x8*)&Bs[((wc * 64 + ni * 16 + (lane & 15)) << 6) + kb];
      #pragma unroll
      for (int mi = 0; mi < 4; ++mi)
        #pragma unroll
        for (int ni = 0; ni < 4; ++ni)
          acc[mi][ni] = __builtin_amdgcn_mfma_f32_16x16x32_bf16(a[mi], b[ni], acc[mi][ni], 0, 0, 0);
    }
    __syncthreads();
  }

  float bb[4];
  #pragma unroll
  for (int ni = 0; ni < 4; ++ni)
    bb[ni] = b1[e * IDIM + n0 + wc * 64 + ni * 16 + (lane & 15)];

  #pragma unroll
  for (int mi = 0; mi < 4; ++mi) {
    int gr0 = wr * 64 + mi * 16 + ((lane >> 4) << 2);
    #pragma unroll
    for (int r2 = 0; r2 < 4; ++r2) {
      int g = gr0 + r2;
      if (g < cntRem) {
        size_t p = (size_t)(row0 + g);
        #pragma unroll
        for (int ni = 0; ni < 4; ++ni) {
          int col = n0 + wc * 64 + ni * 16 + (lane & 15);
          act[p * IDIM + col] = (__bf16)gelu_f(acc[mi][ni][r2] + bb[ni]);
        }
      }
    }
  }
}

// ---------------- K3 gemm2: out[tok] = z[tok] + act @ w2t^T + b2 --------------
// Tile 128x128, BK=64, single-buffer, 8 waves. Expert-XCD affinity: e = bid&7.
#define G2GRID 576
__global__ __launch_bounds__(512) void gemm2_kernel(
    const __bf16* __restrict__ act, const __bf16* __restrict__ w2t,
    const float* __restrict__ b2, const float* __restrict__ z,
    const int* __restrict__ meta, const int* __restrict__ perm,
    float* __restrict__ out) {
  __shared__ __align__(16) char smem[32768];
  __bf16* As = (__bf16*)smem;              // [128][64]
  __bf16* Bs = (__bf16*)(smem + 16384);    // [128][64]
  const int* offs = meta;
  int bid = blockIdx.x;
  int e = bid & 7;
  int r = bid >> 3;                         // 0..71
  int mt = r / 6, nt = r % 6;
  int off0 = offs[e];
  int cnt = offs[e + 1] - off0;
  if ((mt << 7) >= cnt) return;
  int row0 = off0 + (mt << 7);
  int cntRem = cnt - (mt << 7);
  if (cntRem > 128) cntRem = 128;
  int n0 = nt << 7;
  int tid = threadIdx.x, lane = tid & 63, wv = tid >> 6;
  int wr = wv >> 2, wc = wv & 3;
  int swz = ((lane & 7) ^ (lane >> 3)) << 3;

  const __bf16* srcA[2];
  const __bf16* srcB[2];
  #pragma unroll
  for (int i = 0; i < 2; ++i) {
    int row = ((wv * 2 + i) << 3) + (lane >> 3);
    int rA = row < cntRem ? row : cntRem - 1;
    srcA[i] = act + (size_t)(row0 + rA) * IDIM + swz;
    srcB[i] = w2t + ((size_t)e * HDIM + n0 + row) * IDIM + swz;
  }

  int rswz = (lane & 7) << 3;
  f32x4 acc[4][2] = {};

  for (int kk = 0; kk < IDIM / 64; ++kk) {
    #pragma unroll
    for (int i = 0; i < 2; ++i) {
      gload16(As + ((wv * 2 + i) << 9), srcA[i] + kk * 64);
      gload16(Bs + ((wv * 2 + i) << 9), srcB[i] + kk * 64);
    }
    __syncthreads();
    #pragma unroll
    for (int k2 = 0; k2 < 2; ++k2) {
      int kb = (k2 * 32 + ((lane >> 4) << 3)) ^ rswz;
      bf16x8 a[4], b[2];
      #pragma unroll
      for (int mi = 0; mi < 4; ++mi)
        a[mi] = *(const bf16x8*)&As[((wr * 64 + mi * 16 + (lane & 15)) << 6) + kb];
      #pragma unroll
      for (int ni = 0; ni < 2; ++ni)
        b[ni] = *(const bf16x8*)&Bs[((wc * 32 + ni * 16 + (lane & 15)) << 6) + kb];
      #pragma unroll
      for (int mi = 0; mi < 4; ++mi)
        #pragma unroll
        for (int ni = 0; ni < 2; ++ni)
          acc[mi][ni] = __builtin_amdgcn_mfma_f32_16x16x32_bf16(a[mi], b[ni], acc[mi][ni], 0, 0, 0);
    }
    __syncthreads();
  }

  float bb[2];
  #pragma unroll
  for (int ni = 0; ni < 2; ++ni)
    bb[ni] = b2[e * HDIM + n0 + wc * 32 + ni * 16 + (lane & 15)];

  #pragma unroll
  for (int mi = 0; mi < 4; ++mi) {
    int gr0 = wr * 64 + mi * 16 + ((lane >> 4) << 2);
    #pragma unroll
    for (int r2 = 0; r2 < 4; ++r2) {
      int g = gr0 + r2;
      if (g < cntRem) {
        int p = row0 + g;
        int tok = perm[p];
        #pragma unroll
        for (int ni = 0; ni < 2; ++ni) {
          int col = n0 + wc * 32 + ni * 16 + (lane & 15);
          out[(size_t)tok * HDIM + col] =
              z[(size_t)tok * HDIM + col] + acc[mi][ni][r2] + bb[ni];
        }
      }
    }
  }
}

extern "C" void kernel_launch(void* const* d_in, const int* in_sizes, int n_in,
                              void* d_out, int out_size, void* d_ws, size_t ws_size,
                              hipStream_t stream) {
  const float* z  = (const float*)d_in[0];
  const int*   lid = (const int*)d_in[1];
  const float* w1 = (const float*)d_in[2];
  const float* b1 = (const float*)d_in[3];
  const float* w2 = (const float*)d_in[4];
  const float* b2 = (const float*)d_in[5];
  float* out = (float*)d_out;
  char* ws = (char*)d_ws;

  int* meta = (int*)ws;                     // 9 ints
  int* perm = (int*)(ws + 2048);            // NTOK ints
  __bf16* zb  = (__bf16*)(ws + 2048 + 32768);
  __bf16* w1t = zb + (size_t)NTOK * HDIM;
  __bf16* w2t = w1t + (size_t)LNUM * HDIM * IDIM;
  __bf16* act = w2t + (size_t)LNUM * HDIM * IDIM;

  prep_kernel<<<NB_SC + NB_CZ + NB_W, 256, 0, stream>>>(
      lid, z, w1, meta, perm, (bf16x8*)zb, w1t);
  gemm1_kernel<<<G1GRID + NB_W, 512, 0, stream>>>(zb, w1t, b1, meta, perm, act,
                                                  w2, w2t);
  gemm2_kernel<<<G2GRID, 512, 0, stream>>>(act, w2t, b2, z, meta, perm, out);
}